// Round 1
// baseline (10006.992 us; speedup 1.0000x reference)
//
#include <hip/hip_runtime.h>
#include <math.h>

// ---------------------------------------------------------------------------
// STCN forward, fp32 correctness-first baseline.
//   B=4, CK=CV=512, T=3, H=W=24 (THW=1728, HW=576)
// Structure: per-bank [asq -> affinity GEMM -> softmax -> readout GEMM(/sum)]
//            -> pool/mask conv -> decodes -> conv decoder -> pred -> final.
// All convs: direct 3x3, LDS-staged, fused bias/relu-in/sigmoid/residual-add.
// Workspace: 5 overlaid slabs, peak ~104 MiB (ws must be >= 109,178,880 B).
// ---------------------------------------------------------------------------

static constexpr int THW  = 1728;
static constexpr int HW16 = 576;

__device__ __forceinline__ float sigmf(float x) { return 1.f / (1.f + expf(-x)); }

// ---------------- a[b][t] = sum_c mk[b][c][t]^2 ----------------------------
__global__ __launch_bounds__(256) void asq_k(const float* __restrict__ mk,
                                             float* __restrict__ asq) {
  int i = blockIdx.x * 256 + threadIdx.x;
  if (i >= 4 * THW) return;
  int b = i / THW, t = i - b * THW;
  const float* p = mk + (size_t)b * 512 * THW + t;
  float s = 0.f;
  #pragma unroll 4
  for (int c = 0; c < 512; ++c) { float v = p[(size_t)c * THW]; s += v * v; }
  asq[i] = s;
}

// ---------------- 64x64-tile fp32 GEMM, 4x4 micro-tile ---------------------
// AT=false: A is [K][M] (k-major). AT=true: A is [M][K].  B is [K][N].
// EPI==1: C = (2*acc - asq[b*THW+m]) * scale     (affinity logits)
// EPI==2: C = acc / colsum[b*576+n]              (readout, softmax denom)
template<bool AT, int EPI>
__global__ __launch_bounds__(256) void gemm64_k(
    const float* __restrict__ A, const float* __restrict__ Bm,
    float* __restrict__ C, int K, int lda, int ldb, int ldc, int Nt,
    size_t aBS, size_t bBS, size_t cBS,
    const float* __restrict__ asq, float scale, const float* __restrict__ colsum)
{
  const int b  = blockIdx.y;
  const int mt = blockIdx.x / Nt, nt = blockIdx.x - mt * Nt;
  const int m0 = mt * 64, n0 = nt * 64;
  const float* Ab = A + (size_t)b * aBS;
  const float* Bb = Bm + (size_t)b * bBS;
  __shared__ alignas(16) float As[16][68];
  __shared__ alignas(16) float Bs[16][68];
  const int tid = threadIdx.x;
  const int tx = tid & 15, ty = tid >> 4;   // tx -> n (fast), ty -> m
  float acc[4][4] = {};
  for (int k0 = 0; k0 < K; k0 += 16) {
    #pragma unroll
    for (int e = 0; e < 4; ++e) {
      int idx = tid + 256 * e;
      if constexpr (AT) {
        int k = idx & 15, m = idx >> 4;
        As[k][m] = Ab[(size_t)(m0 + m) * lda + (k0 + k)];
      } else {
        int m = idx & 63, k = idx >> 6;
        As[k][m] = Ab[(size_t)(k0 + k) * lda + (m0 + m)];
      }
      int n = idx & 63, k2 = idx >> 6;
      Bs[k2][n] = Bb[(size_t)(k0 + k2) * ldb + (n0 + n)];
    }
    __syncthreads();
    #pragma unroll
    for (int k = 0; k < 16; ++k) {
      float4 av = *reinterpret_cast<const float4*>(&As[k][ty * 4]);
      float4 bv = *reinterpret_cast<const float4*>(&Bs[k][tx * 4]);
      float aq[4] = {av.x, av.y, av.z, av.w};
      float bq[4] = {bv.x, bv.y, bv.z, bv.w};
      #pragma unroll
      for (int i = 0; i < 4; ++i)
        #pragma unroll
        for (int j = 0; j < 4; ++j) acc[i][j] += aq[i] * bq[j];
    }
    __syncthreads();
  }
  float* Cb = C + (size_t)b * cBS;
  #pragma unroll
  for (int i = 0; i < 4; ++i) {
    int m = m0 + ty * 4 + i;
    float4 v;
    float* vp = &v.x;
    if constexpr (EPI == 1) {
      float a = asq[b * THW + m];
      #pragma unroll
      for (int j = 0; j < 4; ++j) vp[j] = (2.f * acc[i][j] - a) * scale;
    } else {
      #pragma unroll
      for (int j = 0; j < 4; ++j)
        vp[j] = acc[i][j] / colsum[b * HW16 + (n0 + tx * 4 + j)];
    }
    *reinterpret_cast<float4*>(&Cb[(size_t)m * ldc + n0 + tx * 4]) = v;
  }
}

// ---------------- softmax over t (rows of S[b][t][n]), in place ------------
// Writes un-normalized exp back into S and the per-column sum into colsum.
__global__ __launch_bounds__(256) void softmax_k(float* __restrict__ S,
                                                 float* __restrict__ colsum) {
  const int b  = blockIdx.y;
  const int tn = threadIdx.x & 15;
  const int tt = threadIdx.x >> 4;
  const int n  = blockIdx.x * 16 + tn;
  float* Sb = S + (size_t)b * THW * HW16;
  float mx = -3.0e38f;
  for (int t = tt; t < THW; t += 16) mx = fmaxf(mx, Sb[(size_t)t * HW16 + n]);
  __shared__ float red[16][17];
  red[tt][tn] = mx;
  __syncthreads();
  if (tt == 0) {
    float m2 = red[0][tn];
    #pragma unroll
    for (int i = 1; i < 16; ++i) m2 = fmaxf(m2, red[i][tn]);
    red[0][tn] = m2;
  }
  __syncthreads();
  mx = red[0][tn];
  float sum = 0.f;
  for (int t = tt; t < THW; t += 16) {
    size_t idx = (size_t)t * HW16 + n;
    float e = expf(Sb[idx] - mx);
    Sb[idx] = e;
    sum += e;
  }
  __syncthreads();
  red[tt][tn] = sum;
  __syncthreads();
  if (tt == 0) {
    float s2 = 0.f;
    #pragma unroll
    for (int i = 0; i < 16; ++i) s2 += red[i][tn];
    colsum[b * HW16 + n] = s2;
  }
}

// ---------------- mean over HW per (b,c) -----------------------------------
__global__ __launch_bounds__(64) void pool_k(const float* __restrict__ fusion,
                                             float* __restrict__ pool) {
  int bc = blockIdx.x;
  const float* p = fusion + (size_t)bc * HW16;
  float s = 0.f;
  for (int i = threadIdx.x; i < HW16; i += 64) s += p[i];
  #pragma unroll
  for (int off = 32; off > 0; off >>= 1) s += __shfl_down(s, off);
  if (threadIdx.x == 0) pool[bc] = s * (1.f / 576.f);
}

__global__ __launch_bounds__(256) void fusionp_k(const float* __restrict__ f,
                                                 const float* __restrict__ pool,
                                                 float* __restrict__ o, int total) {
  int i = blockIdx.x * 256 + threadIdx.x;
  if (i >= total) return;
  o[i] = f[i] + pool[i / HW16];
}

// decodes[:,0:512] = (l+g+a) * (m+1); decodes[:,512:1024] = qv16
__global__ __launch_bounds__(256) void decodes_k(const float* __restrict__ fusion,
                                                 const float* __restrict__ m,
                                                 const float* __restrict__ qv,
                                                 float* __restrict__ out) {
  int i = blockIdx.x * 256 + threadIdx.x;
  if (i >= 4 * 1024 * HW16) return;
  int n = i % HW16; int t = i / HW16; int c = t % 1024; int b = t / 1024;
  float v;
  if (c < 512) {
    const float* f = fusion + (size_t)b * 1536 * HW16;
    float l = f[(size_t)c * HW16 + n];
    float g = f[(size_t)(c + 512) * HW16 + n];
    float a = f[(size_t)(c + 1024) * HW16 + n];
    v = (l + g + a) * (m[((size_t)b * 512 + c) * HW16 + n] + 1.f);
  } else {
    v = qv[((size_t)b * 512 + (c - 512)) * HW16 + n];
  }
  out[i] = v;
}

// ---------------- generic 3x3 SAME conv, LDS-staged ------------------------
// Block: 8x8 spatial tile x (16*G) output channels; 256 threads.
// Thread: 4 consecutive x-pixels x G consecutive cout -> 4*G accumulators.
// RELU_IN applies relu to the input on load; ACT==1 -> sigmoid on output;
// add != nullptr -> out = conv + add (residual); add may alias out.
template<int G, bool RELU_IN, int ACT>
__global__ __launch_bounds__(256) void conv3x3_k(
    const float* __restrict__ in, const float* __restrict__ w,
    const float* __restrict__ bias, const float* add, float* out,
    int Cin, int Cout, int H, int W)
{
  constexpr int COT = 16 * G;
  const int tilesX = W >> 3;
  const int tile = blockIdx.x;
  const int tx0 = (tile % tilesX) << 3;
  const int ty0 = (tile / tilesX) << 3;
  const int co0 = blockIdx.y * COT;
  const int b = blockIdx.z;
  __shared__ alignas(16) float s_in[8][10][12];
  __shared__ alignas(16) float s_w[72][COT + 4];
  const int tid = threadIdx.x;
  const int txg = tid & 15;
  const int tyg = tid >> 4;
  const int p0 = txg << 2;
  const int ly = p0 >> 3;
  const int lx0 = p0 & 7;            // 0 or 4 -> 16B aligned LDS rows
  float acc[G][4];
  #pragma unroll
  for (int q = 0; q < G; ++q)
    #pragma unroll
    for (int j = 0; j < 4; ++j) acc[q][j] = 0.f;
  const size_t HWs = (size_t)H * W;
  const float* inb = in + (size_t)b * Cin * HWs;
  for (int ci0 = 0; ci0 < Cin; ci0 += 8) {
    for (int idx = tid; idx < 800; idx += 256) {        // 8ci x 10 x 10 halo tile
      int ci = idx / 100; int r = idx - ci * 100;
      int iy = r / 10;    int ix = r - iy * 10;
      int gy = ty0 + iy - 1, gx = tx0 + ix - 1;
      float v = 0.f;
      if (gy >= 0 && gy < H && gx >= 0 && gx < W) {
        v = inb[(size_t)(ci0 + ci) * HWs + (size_t)gy * W + gx];
        if (RELU_IN) v = fmaxf(v, 0.f);
      }
      s_in[ci][iy][ix] = v;
    }
    for (int idx = tid; idx < 72 * COT; idx += 256) {   // [ci*9+tap][co]
      int co = idx / 72; int r = idx - co * 72;
      s_w[r][co] = w[((size_t)(co0 + co) * Cin + ci0) * 9 + r];
    }
    __syncthreads();
    #pragma unroll
    for (int ci = 0; ci < 8; ++ci) {
      #pragma unroll
      for (int ky = 0; ky < 3; ++ky) {
        const int yy = ly + ky;
        float4 r4 = *reinterpret_cast<const float4*>(&s_in[ci][yy][lx0]);
        float2 r2 = *reinterpret_cast<const float2*>(&s_in[ci][yy][lx0 + 4]);
        float row[6] = {r4.x, r4.y, r4.z, r4.w, r2.x, r2.y};
        #pragma unroll
        for (int kx = 0; kx < 3; ++kx) {
          const int rr = ci * 9 + ky * 3 + kx;
          float wq[G];
          if constexpr (G == 4) {
            float4 wv = *reinterpret_cast<const float4*>(&s_w[rr][tyg << 2]);
            wq[0] = wv.x; wq[1] = wv.y; wq[2] = wv.z; wq[3] = wv.w;
          } else {
            float2 wv = *reinterpret_cast<const float2*>(&s_w[rr][tyg << 1]);
            wq[0] = wv.x; wq[1] = wv.y;
          }
          #pragma unroll
          for (int q = 0; q < G; ++q)
            #pragma unroll
            for (int j = 0; j < 4; ++j)
              acc[q][j] += wq[q] * row[kx + j];
        }
      }
    }
    __syncthreads();
  }
  #pragma unroll
  for (int q = 0; q < G; ++q) {
    const int co = co0 + tyg * G + q;
    const float bv = bias[co];
    const size_t base = ((size_t)b * Cout + co) * HWs + (size_t)(ty0 + ly) * W + tx0 + lx0;
    float4 v = make_float4(acc[q][0] + bv, acc[q][1] + bv, acc[q][2] + bv, acc[q][3] + bv);
    if (add != nullptr) {
      float4 a4 = *reinterpret_cast<const float4*>(&add[base]);
      v.x += a4.x; v.y += a4.y; v.z += a4.z; v.w += a4.w;
    }
    if (ACT == 1) { v.x = sigmf(v.x); v.y = sigmf(v.y); v.z = sigmf(v.z); v.w = sigmf(v.w); }
    *reinterpret_cast<float4*>(&out[base]) = v;
  }
}

// ---------------- 3x3 conv with Cout==1 (pred head) ------------------------
template<bool RELU_IN>
__global__ __launch_bounds__(256) void conv3x3_co1_k(
    const float* __restrict__ in, const float* __restrict__ w,
    const float* __restrict__ bias, float* __restrict__ out,
    int Cin, int H, int W)
{
  const int tilesX = W >> 4;
  const int tx0 = (blockIdx.x % tilesX) << 4;
  const int ty0 = (blockIdx.x / tilesX) << 4;
  const int b = blockIdx.y;
  __shared__ float s_in[4][18][20];
  __shared__ float s_w[36];
  const int tid = threadIdx.x;
  const int lx = tid & 15, ly = tid >> 4;
  float acc = 0.f;
  const size_t HWs = (size_t)H * W;
  const float* inb = in + (size_t)b * Cin * HWs;
  for (int ci0 = 0; ci0 < Cin; ci0 += 4) {
    for (int idx = tid; idx < 4 * 324; idx += 256) {
      int ci = idx / 324; int r = idx - ci * 324;
      int iy = r / 18;    int ix = r - iy * 18;
      int gy = ty0 + iy - 1, gx = tx0 + ix - 1;
      float v = 0.f;
      if (gy >= 0 && gy < H && gx >= 0 && gx < W) {
        v = inb[(size_t)(ci0 + ci) * HWs + (size_t)gy * W + gx];
        if (RELU_IN) v = fmaxf(v, 0.f);
      }
      s_in[ci][iy][ix] = v;
    }
    if (tid < 36) s_w[tid] = w[(size_t)(ci0 + tid / 9) * 9 + (tid % 9)];
    __syncthreads();
    #pragma unroll
    for (int ci = 0; ci < 4; ++ci)
      #pragma unroll
      for (int ky = 0; ky < 3; ++ky)
        #pragma unroll
        for (int kx = 0; kx < 3; ++kx)
          acc += s_in[ci][ly + ky][lx + kx] * s_w[ci * 9 + ky * 3 + kx];
    __syncthreads();
  }
  out[(size_t)b * HWs + (size_t)(ty0 + ly) * W + tx0 + lx] = acc + bias[0];
}

// ---------------- s += bilinear 2x upsample of x ---------------------------
// jax half-pixel mapping; edge renormalization == index clamping for linear.
__global__ __launch_bounds__(256) void up2add_k(float* __restrict__ s,
                                                const float* __restrict__ x,
                                                int OH, int OW, int total) {
  int i = blockIdx.x * 256 + threadIdx.x;
  if (i >= total) return;
  int ox = i % OW; int t = i / OW; int oy = t % OH; int bc = t / OH;
  int IH = OH >> 1, IW = OW >> 1;
  const float* xp = x + (size_t)bc * IH * IW;
  float uy = 0.5f * oy - 0.25f;
  float ux = 0.5f * ox - 0.25f;
  int y0 = (int)floorf(uy); float fy = uy - (float)y0;
  int x0 = (int)floorf(ux); float fx = ux - (float)x0;
  int y0c = y0 < 0 ? 0 : y0; int y1c = (y0 + 1 >= IH) ? IH - 1 : y0 + 1;
  int x0c = x0 < 0 ? 0 : x0; int x1c = (x0 + 1 >= IW) ? IW - 1 : x0 + 1;
  float v00 = xp[y0c * IW + x0c], v01 = xp[y0c * IW + x1c];
  float v10 = xp[y1c * IW + x0c], v11 = xp[y1c * IW + x1c];
  s[i] += (1.f - fy) * ((1.f - fx) * v00 + fx * v01)
        + fy * ((1.f - fx) * v10 + fx * v11);
}

// ---------------- bilinear 4x + sigmoid/aggregate/output -------------------
__global__ __launch_bounds__(256) void final_k(const float* __restrict__ l4,
                                               float* __restrict__ out) {
  int i = blockIdx.x * 256 + threadIdx.x;
  if (i >= 4 * 384 * 384) return;
  int ox = i % 384; int t = i / 384; int oy = t % 384; int b = t / 384;
  const float* lp = l4 + (size_t)b * 96 * 96;
  float uy = 0.25f * oy - 0.375f;
  float ux = 0.25f * ox - 0.375f;
  int y0 = (int)floorf(uy); float fy = uy - (float)y0;
  int x0 = (int)floorf(ux); float fx = ux - (float)x0;
  int y0c = y0 < 0 ? 0 : y0; int y1c = (y0 + 1 > 95) ? 95 : y0 + 1;
  int x0c = x0 < 0 ? 0 : x0; int x1c = (x0 + 1 > 95) ? 95 : x0 + 1;
  float l = (1.f - fy) * ((1.f - fx) * lp[y0c * 96 + x0c] + fx * lp[y0c * 96 + x1c])
          + fy * ((1.f - fx) * lp[y1c * 96 + x0c] + fx * lp[y1c * 96 + x1c]);
  float p  = 1.f / (1.f + expf(-l));
  float p1 = fminf(fmaxf(p, 1e-7f), 1.f - 1e-7f);
  float p0 = fminf(fmaxf(1.f - p, 1e-7f), 1.f - 1e-7f);
  float L0 = logf(p0 / (1.f - p0));
  float L1 = logf(p1 / (1.f - p1));
  int sp = oy * 384 + ox;
  out[(size_t)(b * 2) * 147456 + sp] = L0;
  out[(size_t)(b * 2 + 1) * 147456 + sp] = L1;
  out[(size_t)1179648 + (size_t)b * 147456 + sp] = 1.f / (1.f + expf(L0 - L1));
}

// ---------------------------------------------------------------------------
extern "C" void kernel_launch(void* const* d_in, const int* in_sizes, int n_in,
                              void* d_out, int out_size, void* d_ws, size_t ws_size,
                              hipStream_t stream)
{
  (void)in_sizes; (void)n_in; (void)out_size; (void)ws_size;
  const float* qk16   = (const float*)d_in[0];
  const float* qv16   = (const float*)d_in[1];
  const float* qf8    = (const float*)d_in[2];
  const float* qf4    = (const float*)d_in[3];
  const float* mk16   = (const float*)d_in[4];
  const float* mv16   = (const float*)d_in[5];
  const float* firstk = (const float*)d_in[6];
  const float* firstv = (const float*)d_in[7];
  const float* adjk   = (const float*)d_in[8];
  const float* adfv   = (const float*)d_in[9];
  const float* mask_w   = (const float*)d_in[10];
  const float* mask_b   = (const float*)d_in[11];
  const float* cmp_ds_w = (const float*)d_in[12];
  const float* cmp_ds_b = (const float*)d_in[13];
  const float* cmp_c1_w = (const float*)d_in[14];
  const float* cmp_c1_b = (const float*)d_in[15];
  const float* cmp_c2_w = (const float*)d_in[16];
  const float* cmp_c2_b = (const float*)d_in[17];
  const float* u1_skip_w = (const float*)d_in[18];
  const float* u1_skip_b = (const float*)d_in[19];
  const float* u1_ds_w   = (const float*)d_in[20];
  const float* u1_ds_b   = (const float*)d_in[21];
  const float* u1_c1_w   = (const float*)d_in[22];
  const float* u1_c1_b   = (const float*)d_in[23];
  const float* u1_c2_w   = (const float*)d_in[24];
  const float* u1_c2_b   = (const float*)d_in[25];
  const float* u2_skip_w = (const float*)d_in[26];
  const float* u2_skip_b = (const float*)d_in[27];
  const float* u2_c1_w   = (const float*)d_in[28];
  const float* u2_c1_b   = (const float*)d_in[29];
  const float* u2_c2_w   = (const float*)d_in[30];
  const float* u2_c2_b   = (const float*)d_in[31];
  const float* pred_w    = (const float*)d_in[32];
  const float* pred_b    = (const float*)d_in[33];
  float* ws  = (float*)d_ws;
  float* out = (float*)d_out;

  // Overlaid slabs (floats). Peak ws ~104.1 MiB.
  float* slabA = ws;                  // 9,437,184 : aff -> fusionp -> t1_16/t1_8/t1_4
  float* slabB = slabA + 9437184;     // 9,437,184 : t2_16/t2_8 -> s4/x4
  float* slabC = slabB + 9437184;     // 4,718,592 : fusion -> s8
  float* slabD = slabC + 4718592;     // 1,179,648 : m -> x16
  float* slabE = slabD + 1179648;     // 2,359,296 : decodes -> x8
  float* smll  = slabE + 2359296;
  float* asq    = smll;               // 6,912
  float* colsum = smll + 6912;        // 2,304
  float* pool   = smll + 9216;        // 6,144
  float* l4     = smll + 15360;       // 147,456

  float* aff    = slabA;
  float* fusion = slabC;
  const float scale = 0.04419417382415922f;   // 1/sqrt(512)

  const float* banksK[3] = {mk16, firstk, adjk};
  const float* banksV[3] = {mv16, firstv, adfv};
  for (int bank = 0; bank < 3; ++bank) {
    asq_k<<<27, 256, 0, stream>>>(banksK[bank], asq);
    // S[b][t][n] = (2*mk^T qk - a)/sqrt(ck):  M=t=1728, N=n=576, K=c=512
    gemm64_k<false, 1><<<dim3(27 * 9, 4), 256, 0, stream>>>(
        banksK[bank], qk16, aff, 512, THW, HW16, HW16, 9,
        (size_t)512 * THW, (size_t)512 * HW16, (size_t)THW * HW16,
        asq, scale, nullptr);
    softmax_k<<<dim3(36, 4), 256, 0, stream>>>(aff, colsum);
    // mem[b][c][n] = mv . exp / colsum:  M=c=512, N=n=576, K=t=1728
    gemm64_k<true, 2><<<dim3(8 * 9, 4), 256, 0, stream>>>(
        banksV[bank], aff, fusion + (size_t)bank * 512 * HW16,
        THW, THW, HW16, HW16, 9,
        (size_t)512 * THW, (size_t)THW * HW16, (size_t)1536 * HW16,
        nullptr, 0.f, colsum);
  }

  pool_k<<<4 * 1536, 64, 0, stream>>>(fusion, pool);
  float* fusionp = slabA;             // aff dead
  fusionp_k<<<(3538944 + 255) / 256, 256, 0, stream>>>(fusion, pool, fusionp, 3538944);
  float* mbuf = slabD;
  conv3x3_k<2, false, 1><<<dim3(9, 16, 4), 256, 0, stream>>>(
      fusionp, mask_w, mask_b, nullptr, mbuf, 1536, 512, 24, 24);
  float* dec = slabE;
  decodes_k<<<(2359296 + 255) / 256, 256, 0, stream>>>(fusion, mbuf, qv16, dec);

  float* t1 = slabA;                  // fusionp dead
  float* t2 = slabB;
  conv3x3_k<2, true, 0><<<dim3(9, 16, 4), 256, 0, stream>>>(
      dec, cmp_c1_w, cmp_c1_b, nullptr, t1, 1024, 512, 24, 24);
  conv3x3_k<2, true, 0><<<dim3(9, 16, 4), 256, 0, stream>>>(
      t1, cmp_c2_w, cmp_c2_b, nullptr, t2, 512, 512, 24, 24);
  float* x16 = slabD;                 // m dead
  conv3x3_k<2, false, 0><<<dim3(9, 16, 4), 256, 0, stream>>>(
      dec, cmp_ds_w, cmp_ds_b, t2, x16, 1024, 512, 24, 24);

  float* s8 = slabC;                  // fusion dead
  conv3x3_k<4, false, 0><<<dim3(36, 8, 4), 256, 0, stream>>>(
      qf8, u1_skip_w, u1_skip_b, nullptr, s8, 512, 512, 48, 48);
  up2add_k<<<(4718592 + 255) / 256, 256, 0, stream>>>(s8, x16, 48, 48, 4718592);
  conv3x3_k<4, true, 0><<<dim3(36, 4, 4), 256, 0, stream>>>(
      s8, u1_c1_w, u1_c1_b, nullptr, t1, 512, 256, 48, 48);
  conv3x3_k<4, true, 0><<<dim3(36, 4, 4), 256, 0, stream>>>(
      t1, u1_c2_w, u1_c2_b, nullptr, t2, 256, 256, 48, 48);
  float* x8 = slabE;                  // decodes dead
  conv3x3_k<4, false, 0><<<dim3(36, 4, 4), 256, 0, stream>>>(
      s8, u1_ds_w, u1_ds_b, t2, x8, 512, 256, 48, 48);

  float* s4 = slabB;                  // t2_8 dead
  conv3x3_k<4, false, 0><<<dim3(144, 4, 4), 256, 0, stream>>>(
      qf4, u2_skip_w, u2_skip_b, nullptr, s4, 256, 256, 96, 96);
  up2add_k<<<(9437184 + 255) / 256, 256, 0, stream>>>(s4, x8, 96, 96, 9437184);
  conv3x3_k<4, true, 0><<<dim3(144, 4, 4), 256, 0, stream>>>(
      s4, u2_c1_w, u2_c1_b, nullptr, t1, 256, 256, 96, 96);
  // x4 = s4 + conv(relu(t1)); in-place add into s4 (each elem touched once)
  conv3x3_k<4, true, 0><<<dim3(144, 4, 4), 256, 0, stream>>>(
      t1, u2_c2_w, u2_c2_b, s4, s4, 256, 256, 96, 96);

  conv3x3_co1_k<true><<<dim3(36, 4), 256, 0, stream>>>(s4, pred_w, pred_b, l4, 256, 96, 96);
  final_k<<<(589824 + 255) / 256, 256, 0, stream>>>(l4, out);
}

// Round 2
// 2300.821 us; speedup vs baseline: 4.3493x; 4.3493x over previous
//
#include <hip/hip_runtime.h>
#include <math.h>

// ---------------------------------------------------------------------------
// STCN forward. Round 2: all 3x3 convs -> bf16 MFMA implicit GEMM (NHWC),
// affinity/softmax/readout kept fp32. B=4, CK=CV=512, T=3, H=W=24.
// ---------------------------------------------------------------------------

static constexpr int THW  = 1728;
static constexpr int HW16 = 576;

typedef __attribute__((ext_vector_type(8))) short bf16x8;
typedef __attribute__((ext_vector_type(4))) float f32x4;
typedef unsigned int uint;
typedef unsigned short ushortx;

__device__ __forceinline__ float sigmf(float x) { return 1.f / (1.f + expf(-x)); }

__device__ __forceinline__ float bf2f(unsigned short u) {
  union { float f; uint i; } x; x.i = ((uint)u) << 16; return x.f;
}
__device__ __forceinline__ unsigned short f2bf(float f) {
  union { float f; uint i; } x; x.f = f;
  uint r = x.i + 0x7fffu + ((x.i >> 16) & 1u);
  return (unsigned short)(r >> 16);
}
__device__ __forceinline__ uint relu2(uint x) {
  uint lo = (x & 0x8000u) ? 0u : (x & 0xFFFFu);
  uint hi = (x & 0x80000000u) ? 0u : (x & 0xFFFF0000u);
  return lo | hi;
}
__device__ __forceinline__ bf16x8 lds_ld8(const unsigned short* p) {
  union { uint2 u2[2]; bf16x8 v; } x;
  x.u2[0] = *(const uint2*)(p);
  x.u2[1] = *(const uint2*)(p + 4);
  return x.v;
}

// ---------------- a[b][t] = sum_c mk[b][c][t]^2 ----------------------------
__global__ __launch_bounds__(256) void asq_k(const float* __restrict__ mk,
                                             float* __restrict__ asq) {
  int i = blockIdx.x * 256 + threadIdx.x;
  if (i >= 4 * THW) return;
  int b = i / THW, t = i - b * THW;
  const float* p = mk + (size_t)b * 512 * THW + t;
  float s = 0.f;
  #pragma unroll 4
  for (int c = 0; c < 512; ++c) { float v = p[(size_t)c * THW]; s += v * v; }
  asq[i] = s;
}

// ---------------- 64x64-tile fp32 GEMM, 4x4 micro-tile ---------------------
// AT=false: A is [K][M]. AT=true: A is [M][K]. B is [K][N].
// EPI==1: C[m][n] = (2*acc - asq[b*THW+m]) * scale, row-major [m][n], ldc
// EPI==2: C stored TRANSPOSED NHWC: C[n][cOff+m] = acc / colsum[b*576+n], ldc=row stride
template<bool AT, int EPI>
__global__ __launch_bounds__(256) void gemm64_k(
    const float* __restrict__ A, const float* __restrict__ Bm,
    float* __restrict__ C, int K, int lda, int ldb, int ldc, int Nt,
    size_t aBS, size_t bBS, size_t cBS,
    const float* __restrict__ asq, float scale, const float* __restrict__ colsum,
    int cOff)
{
  const int b  = blockIdx.y;
  const int mt = blockIdx.x / Nt, nt = blockIdx.x - mt * Nt;
  const int m0 = mt * 64, n0 = nt * 64;
  const float* Ab = A + (size_t)b * aBS;
  const float* Bb = Bm + (size_t)b * bBS;
  __shared__ alignas(16) float As[16][68];
  __shared__ alignas(16) float Bs[16][68];
  const int tid = threadIdx.x;
  const int tx = tid & 15, ty = tid >> 4;
  float acc[4][4] = {};
  for (int k0 = 0; k0 < K; k0 += 16) {
    #pragma unroll
    for (int e = 0; e < 4; ++e) {
      int idx = tid + 256 * e;
      if constexpr (AT) {
        int k = idx & 15, m = idx >> 4;
        As[k][m] = Ab[(size_t)(m0 + m) * lda + (k0 + k)];
      } else {
        int m = idx & 63, k = idx >> 6;
        As[k][m] = Ab[(size_t)(k0 + k) * lda + (m0 + m)];
      }
      int n = idx & 63, k2 = idx >> 6;
      Bs[k2][n] = Bb[(size_t)(k0 + k2) * ldb + (n0 + n)];
    }
    __syncthreads();
    #pragma unroll
    for (int k = 0; k < 16; ++k) {
      float4 av = *reinterpret_cast<const float4*>(&As[k][ty * 4]);
      float4 bv = *reinterpret_cast<const float4*>(&Bs[k][tx * 4]);
      float aq[4] = {av.x, av.y, av.z, av.w};
      float bq[4] = {bv.x, bv.y, bv.z, bv.w};
      #pragma unroll
      for (int i = 0; i < 4; ++i)
        #pragma unroll
        for (int j = 0; j < 4; ++j) acc[i][j] += aq[i] * bq[j];
    }
    __syncthreads();
  }
  float* Cb = C + (size_t)b * cBS;
  if constexpr (EPI == 1) {
    #pragma unroll
    for (int i = 0; i < 4; ++i) {
      int m = m0 + ty * 4 + i;
      float a = asq[b * THW + m];
      float4 v;
      v.x = (2.f * acc[i][0] - a) * scale;
      v.y = (2.f * acc[i][1] - a) * scale;
      v.z = (2.f * acc[i][2] - a) * scale;
      v.w = (2.f * acc[i][3] - a) * scale;
      *reinterpret_cast<float4*>(&Cb[(size_t)m * ldc + n0 + tx * 4]) = v;
    }
  } else {
    #pragma unroll
    for (int j = 0; j < 4; ++j) {
      int n = n0 + tx * 4 + j;
      float inv = 1.f / colsum[b * HW16 + n];
      float4 v;
      v.x = acc[0][j] * inv; v.y = acc[1][j] * inv;
      v.z = acc[2][j] * inv; v.w = acc[3][j] * inv;
      *reinterpret_cast<float4*>(&Cb[(size_t)n * ldc + cOff + m0 + ty * 4]) = v;
    }
  }
}

// ---------------- softmax over t, in place; colsum out ---------------------
__global__ __launch_bounds__(256) void softmax_k(float* __restrict__ S,
                                                 float* __restrict__ colsum) {
  const int b  = blockIdx.y;
  const int tn = threadIdx.x & 15;
  const int tt = threadIdx.x >> 4;
  const int n  = blockIdx.x * 16 + tn;
  float* Sb = S + (size_t)b * THW * HW16;
  float mx = -3.0e38f;
  for (int t = tt; t < THW; t += 16) mx = fmaxf(mx, Sb[(size_t)t * HW16 + n]);
  __shared__ float red[16][17];
  red[tt][tn] = mx;
  __syncthreads();
  if (tt == 0) {
    float m2 = red[0][tn];
    #pragma unroll
    for (int i = 1; i < 16; ++i) m2 = fmaxf(m2, red[i][tn]);
    red[0][tn] = m2;
  }
  __syncthreads();
  mx = red[0][tn];
  float sum = 0.f;
  for (int t = tt; t < THW; t += 16) {
    size_t idx = (size_t)t * HW16 + n;
    float e = expf(Sb[idx] - mx);
    Sb[idx] = e;
    sum += e;
  }
  __syncthreads();
  red[tt][tn] = sum;
  __syncthreads();
  if (tt == 0) {
    float s2 = 0.f;
    #pragma unroll
    for (int i = 0; i < 16; ++i) s2 += red[i][tn];
    colsum[b * HW16 + n] = s2;
  }
}

// ---------------- pool over pixels of NHWC fusion --------------------------
__global__ __launch_bounds__(128) void pool_k(const float* __restrict__ f,
                                              float* __restrict__ pool) {
  int b = blockIdx.y, c = blockIdx.x * 128 + threadIdx.x;
  const float* p = f + (size_t)b * HW16 * 1536 + c;
  float s = 0.f;
  for (int n = 0; n < HW16; ++n) s += p[(size_t)n * 1536];
  pool[b * 1536 + c] = s * (1.f / 576.f);
}

// fusionp = bf16(fusion + pool), NHWC
__global__ __launch_bounds__(256) void fusionp_k(const float* __restrict__ f,
                                                 const float* __restrict__ pool,
                                                 unsigned short* __restrict__ o, int total) {
  int i = blockIdx.x * 256 + threadIdx.x;
  if (i >= total) return;
  int c = i % 1536; int b = i / (HW16 * 1536);
  o[i] = f2bf(f[i] + pool[b * 1536 + c]);
}

// dec NHWC bf16 [b][n][1024]: c<512 -> (l+g+a)*(m+1); else qv16 (CHW fp32)
__global__ __launch_bounds__(256) void decodes_k(const float* __restrict__ fusion,
                                                 const unsigned short* __restrict__ m,
                                                 const float* __restrict__ qv,
                                                 unsigned short* __restrict__ o) {
  int i = blockIdx.x * 256 + threadIdx.x;
  if (i >= 4 * HW16 * 1024) return;
  int c = i & 1023; int t = i >> 10; int n = t % HW16; int b = t / HW16;
  float v;
  if (c < 512) {
    const float* f = fusion + ((size_t)b * HW16 + n) * 1536;
    float s3 = f[c] + f[c + 512] + f[c + 1024];
    float mf = bf2f(m[((size_t)b * HW16 + n) * 512 + c]);
    v = s3 * (mf + 1.f);
  } else {
    v = qv[((size_t)b * 512 + (c - 512)) * HW16 + n];
  }
  o[i] = f2bf(v);
}

// ---------------- NCHW fp32 -> NHWC bf16 transpose -------------------------
__global__ __launch_bounds__(256) void tr_k(const float* __restrict__ in,
                                            unsigned short* __restrict__ out,
                                            int C, int HW) {
  __shared__ float t[32][33];
  int p0 = blockIdx.x << 5, c0 = blockIdx.y << 5, b = blockIdx.z;
  int tx = threadIdx.x & 31, ty = threadIdx.x >> 5;
  const float* ib = in + (size_t)b * C * HW;
  #pragma unroll
  for (int e = 0; e < 4; ++e)
    t[ty + e * 8][tx] = ib[(size_t)(c0 + ty + e * 8) * HW + p0 + tx];
  __syncthreads();
  unsigned short* ob = out + (size_t)b * C * HW;
  #pragma unroll
  for (int e = 0; e < 4; ++e)
    ob[(size_t)(p0 + ty + e * 8) * C + c0 + tx] = f2bf(t[tx][ty + e * 8]);
}

// ---------------- weight repack OIHW fp32 -> [tap][co][ci] bf16 ------------
__global__ __launch_bounds__(256) void wrep_k(const float* __restrict__ w,
                                              unsigned short* __restrict__ o,
                                              int Cout, int Cin, int total) {
  int i = blockIdx.x * 256 + threadIdx.x;
  if (i >= total) return;
  int ci = i % Cin; int t = i / Cin; int co = t % Cout; int tap = t / Cout;
  o[i] = f2bf(w[((size_t)co * Cin + ci) * 9 + tap]);
}

// ---------------- MFMA conv3x3, NHWC bf16 ----------------------------------
// Block: 64 co x 64 pix (8x8 tile), 4 waves of 32x32. K-loop over ci, 9 taps
// from one LDS halo tile. SPLITK: fp32 partials [split][b][HW][Cout]; else
// fused bias/(+add)/(sigmoid) epilogue -> bf16 NHWC.
template<bool RELU_IN, int ACT, bool SPLITK, bool HAS_ADD>
__global__ __launch_bounds__(256) void convmf_k(
    const unsigned short* __restrict__ in, const unsigned short* __restrict__ W2,
    const float* __restrict__ bias, const unsigned short* __restrict__ add,
    unsigned short* __restrict__ outb, float* __restrict__ outp,
    int Cin, int Cout, int H, int W, int ciPer)
{
  const int tilesX = W >> 3;
  const int tx0 = (blockIdx.x % tilesX) << 3;
  const int ty0 = (blockIdx.x / tilesX) << 3;
  const int co0 = blockIdx.y << 6;
  const int b = blockIdx.z & 3;
  const int split = blockIdx.z >> 2;
  const int HWp = H * W;
  __shared__ unsigned short sA[9][64][36];   // [tap][co][ci] pad36
  __shared__ unsigned short sB[100][36];     // [halo pix][ci] pad36
  const int tid = threadIdx.x;
  const int lane = tid & 63, wv = tid >> 6;
  const int cS = (wv >> 1) << 5;   // wave co-subtile base (0/32)
  const int nS = (wv & 1) << 5;    // wave pix-subtile base (0/32)
  const int l15 = lane & 15, lq = lane >> 4;
  int hp0[2], gp[2];
  #pragma unroll
  for (int j = 0; j < 2; ++j) {
    int n = nS + j * 16 + l15;
    int py = n >> 3, px = n & 7;
    hp0[j] = py * 10 + px;
    gp[j] = (ty0 + py) * W + tx0 + px;
  }
  f32x4 acc[2][2];
  #pragma unroll
  for (int i = 0; i < 2; ++i)
    #pragma unroll
    for (int j = 0; j < 2; ++j) acc[i][j] = (f32x4){0.f, 0.f, 0.f, 0.f};
  const size_t inBase = (size_t)b * HWp * Cin;
  const int kLo = split * ciPer, kHi = kLo + ciPer;
  const int sco = tid >> 2;
  const int sc8 = (tid & 3) << 3;
  for (int k0 = kLo; k0 < kHi; k0 += 32) {
    // stage A: [9][64][32]
    #pragma unroll
    for (int tap = 0; tap < 9; ++tap) {
      const uint4 v = *(const uint4*)(W2 + ((size_t)(tap * Cout + co0 + sco) * Cin + k0 + sc8));
      *(uint2*)&sA[tap][sco][sc8]     = make_uint2(v.x, v.y);
      *(uint2*)&sA[tap][sco][sc8 + 4] = make_uint2(v.z, v.w);
    }
    // stage B: 10x10 halo x 32 ci
    #pragma unroll
    for (int e = 0; e < 2; ++e) {
      int idx = tid + (e << 8);
      if (idx < 400) {
        int hp = idx >> 2, c8 = (idx & 3) << 3;
        int hy = ty0 + (hp / 10) - 1;
        int hx = tx0 + (hp % 10) - 1;
        uint4 v = make_uint4(0u, 0u, 0u, 0u);
        if (hy >= 0 && hy < H && hx >= 0 && hx < W)
          v = *(const uint4*)(in + inBase + (size_t)(hy * W + hx) * Cin + k0 + c8);
        if (RELU_IN) { v.x = relu2(v.x); v.y = relu2(v.y); v.z = relu2(v.z); v.w = relu2(v.w); }
        *(uint2*)&sB[hp][c8]     = make_uint2(v.x, v.y);
        *(uint2*)&sB[hp][c8 + 4] = make_uint2(v.z, v.w);
      }
    }
    __syncthreads();
    const int DT[9] = {0, 1, 2, 10, 11, 12, 20, 21, 22};
    #pragma unroll
    for (int tap = 0; tap < 9; ++tap) {
      bf16x8 a0 = lds_ld8(&sA[tap][cS + l15][lq << 3]);
      bf16x8 a1 = lds_ld8(&sA[tap][cS + 16 + l15][lq << 3]);
      bf16x8 b0 = lds_ld8(&sB[hp0[0] + DT[tap]][lq << 3]);
      bf16x8 b1 = lds_ld8(&sB[hp0[1] + DT[tap]][lq << 3]);
      acc[0][0] = __builtin_amdgcn_mfma_f32_16x16x32_bf16(a0, b0, acc[0][0], 0, 0, 0);
      acc[0][1] = __builtin_amdgcn_mfma_f32_16x16x32_bf16(a0, b1, acc[0][1], 0, 0, 0);
      acc[1][0] = __builtin_amdgcn_mfma_f32_16x16x32_bf16(a1, b0, acc[1][0], 0, 0, 0);
      acc[1][1] = __builtin_amdgcn_mfma_f32_16x16x32_bf16(a1, b1, acc[1][1], 0, 0, 0);
    }
    __syncthreads();
  }
  #pragma unroll
  for (int i = 0; i < 2; ++i) {
    const int coB = co0 + cS + i * 16 + (lq << 2);
    #pragma unroll
    for (int j = 0; j < 2; ++j) {
      if constexpr (SPLITK) {
        float* dst = outp + ((size_t)(split * 4 + b) * HWp + gp[j]) * Cout + coB;
        float4 v; v.x = acc[i][j][0]; v.y = acc[i][j][1]; v.z = acc[i][j][2]; v.w = acc[i][j][3];
        *(float4*)dst = v;
      } else {
        float4 bv = *(const float4*)(bias + coB);
        float v0 = acc[i][j][0] + bv.x, v1 = acc[i][j][1] + bv.y;
        float v2 = acc[i][j][2] + bv.z, v3 = acc[i][j][3] + bv.w;
        const size_t base = ((size_t)b * HWp + gp[j]) * Cout + coB;
        if constexpr (HAS_ADD) {
          ushort4 a4 = *(const ushort4*)(add + base);
          v0 += bf2f(a4.x); v1 += bf2f(a4.y); v2 += bf2f(a4.z); v3 += bf2f(a4.w);
        }
        if constexpr (ACT == 1) { v0 = sigmf(v0); v1 = sigmf(v1); v2 = sigmf(v2); v3 = sigmf(v3); }
        ushort4 o; o.x = f2bf(v0); o.y = f2bf(v1); o.z = f2bf(v2); o.w = f2bf(v3);
        *(ushort4*)(outb + base) = o;
      }
    }
  }
}

// ---------------- split-K reduce + epilogue --------------------------------
template<int ACT, bool HAS_ADD>
__global__ __launch_bounds__(256) void skred_k(
    const float* __restrict__ part, const float* __restrict__ bias,
    const unsigned short* __restrict__ add, unsigned short* __restrict__ out,
    int Cout, int n)
{
  int i = blockIdx.x * 256 + threadIdx.x;
  if (i >= n) return;
  float v = part[i] + part[i + n] + bias[i % Cout];
  if (HAS_ADD) v += bf2f(add[i]);
  if (ACT == 1) v = sigmf(v);
  out[i] = f2bf(v);
}

// ---------------- s += bilinear 2x upsample (NHWC bf16) --------------------
__global__ __launch_bounds__(256) void up2add_k(unsigned short* __restrict__ s,
                                                const unsigned short* __restrict__ x,
                                                int OH, int OW, int C, int total) {
  int i = blockIdx.x * 256 + threadIdx.x;
  if (i >= total) return;
  int c = i % C; int op = i / C;
  int ox = op % OW; int t = op / OW; int oy = t % OH; int b = t / OH;
  int IH = OH >> 1, IW = OW >> 1;
  const unsigned short* xp = x + ((size_t)b * IH * IW) * C + c;
  float uy = 0.5f * oy - 0.25f;
  float ux = 0.5f * ox - 0.25f;
  int y0 = (int)floorf(uy); float fy = uy - (float)y0;
  int x0 = (int)floorf(ux); float fx = ux - (float)x0;
  int y0c = y0 < 0 ? 0 : y0; int y1c = (y0 + 1 >= IH) ? IH - 1 : y0 + 1;
  int x0c = x0 < 0 ? 0 : x0; int x1c = (x0 + 1 >= IW) ? IW - 1 : x0 + 1;
  float v00 = bf2f(xp[(size_t)(y0c * IW + x0c) * C]);
  float v01 = bf2f(xp[(size_t)(y0c * IW + x1c) * C]);
  float v10 = bf2f(xp[(size_t)(y1c * IW + x0c) * C]);
  float v11 = bf2f(xp[(size_t)(y1c * IW + x1c) * C]);
  float r = (1.f - fy) * ((1.f - fx) * v00 + fx * v01)
          + fy * ((1.f - fx) * v10 + fx * v11);
  s[i] = f2bf(bf2f(s[i]) + r);
}

// ---------------- pred head: 256->1 conv, relu-in, NHWC bf16 ---------------
__global__ __launch_bounds__(256) void pred_k(const unsigned short* __restrict__ in,
                                              const float* __restrict__ w,
                                              const float* __restrict__ bias,
                                              float* __restrict__ l4) {
  __shared__ float sw[9][256];
  for (int idx = threadIdx.x; idx < 2304; idx += 256)
    sw[idx % 9][idx / 9] = w[idx];
  __syncthreads();
  int gpix = blockIdx.x * 4 + (threadIdx.x >> 6);
  int b = gpix / 9216, pix = gpix % 9216;
  int py = pix / 96, px = pix % 96;
  int lane = threadIdx.x & 63;
  float acc = 0.f;
  #pragma unroll
  for (int ky = 0; ky < 3; ++ky) {
    int gy = py + ky - 1; if (gy < 0 || gy > 95) continue;
    #pragma unroll
    for (int kx = 0; kx < 3; ++kx) {
      int gx = px + kx - 1; if (gx < 0 || gx > 95) continue;
      const unsigned short* ip = in + ((size_t)b * 9216 + gy * 96 + gx) * 256;
      const float* wp = sw[ky * 3 + kx];
      #pragma unroll
      for (int cq = 0; cq < 4; ++cq) {
        int c = lane + (cq << 6);
        acc += fmaxf(bf2f(ip[c]), 0.f) * wp[c];
      }
    }
  }
  #pragma unroll
  for (int off = 32; off > 0; off >>= 1) acc += __shfl_down(acc, off);
  if (lane == 0) l4[gpix] = acc + bias[0];
}

// ---------------- bilinear 4x + sigmoid/aggregate/output -------------------
__global__ __launch_bounds__(256) void final_k(const float* __restrict__ l4,
                                               float* __restrict__ out) {
  int i = blockIdx.x * 256 + threadIdx.x;
  if (i >= 4 * 384 * 384) return;
  int ox = i % 384; int t = i / 384; int oy = t % 384; int b = t / 384;
  const float* lp = l4 + (size_t)b * 96 * 96;
  float uy = 0.25f * oy - 0.375f;
  float ux = 0.25f * ox - 0.375f;
  int y0 = (int)floorf(uy); float fy = uy - (float)y0;
  int x0 = (int)floorf(ux); float fx = ux - (float)x0;
  int y0c = y0 < 0 ? 0 : y0; int y1c = (y0 + 1 > 95) ? 95 : y0 + 1;
  int x0c = x0 < 0 ? 0 : x0; int x1c = (x0 + 1 > 95) ? 95 : x0 + 1;
  float l = (1.f - fy) * ((1.f - fx) * lp[y0c * 96 + x0c] + fx * lp[y0c * 96 + x1c])
          + fy * ((1.f - fx) * lp[y1c * 96 + x0c] + fx * lp[y1c * 96 + x1c]);
  float p  = 1.f / (1.f + expf(-l));
  float p1 = fminf(fmaxf(p, 1e-7f), 1.f - 1e-7f);
  float p0 = fminf(fmaxf(1.f - p, 1e-7f), 1.f - 1e-7f);
  float L0 = logf(p0 / (1.f - p0));
  float L1 = logf(p1 / (1.f - p1));
  int sp = oy * 384 + ox;
  out[(size_t)(b * 2) * 147456 + sp] = L0;
  out[(size_t)(b * 2 + 1) * 147456 + sp] = L1;
  out[(size_t)1179648 + (size_t)b * 147456 + sp] = 1.f / (1.f + expf(L0 - L1));
}

// ---------------------------------------------------------------------------
extern "C" void kernel_launch(void* const* d_in, const int* in_sizes, int n_in,
                              void* d_out, int out_size, void* d_ws, size_t ws_size,
                              hipStream_t stream)
{
  (void)in_sizes; (void)n_in; (void)out_size; (void)ws_size;
  const float* qk16   = (const float*)d_in[0];
  const float* qv16   = (const float*)d_in[1];
  const float* qf8    = (const float*)d_in[2];
  const float* qf4    = (const float*)d_in[3];
  const float* mk16   = (const float*)d_in[4];
  const float* mv16   = (const float*)d_in[5];
  const float* firstk = (const float*)d_in[6];
  const float* firstv = (const float*)d_in[7];
  const float* adjk   = (const float*)d_in[8];
  const float* adfv   = (const float*)d_in[9];
  const float* mask_w   = (const float*)d_in[10];
  const float* mask_b   = (const float*)d_in[11];
  const float* cmp_ds_w = (const float*)d_in[12];
  const float* cmp_ds_b = (const float*)d_in[13];
  const float* cmp_c1_w = (const float*)d_in[14];
  const float* cmp_c1_b = (const float*)d_in[15];
  const float* cmp_c2_w = (const float*)d_in[16];
  const float* cmp_c2_b = (const float*)d_in[17];
  const float* u1_skip_w = (const float*)d_in[18];
  const float* u1_skip_b = (const float*)d_in[19];
  const float* u1_ds_w   = (const float*)d_in[20];
  const float* u1_ds_b   = (const float*)d_in[21];
  const float* u1_c1_w   = (const float*)d_in[22];
  const float* u1_c1_b   = (const float*)d_in[23];
  const float* u1_c2_w   = (const float*)d_in[24];
  const float* u1_c2_b   = (const float*)d_in[25];
  const float* u2_skip_w = (const float*)d_in[26];
  const float* u2_skip_b = (const float*)d_in[27];
  const float* u2_c1_w   = (const float*)d_in[28];
  const float* u2_c1_b   = (const float*)d_in[29];
  const float* u2_c2_w   = (const float*)d_in[30];
  const float* u2_c2_b   = (const float*)d_in[31];
  const float* pred_w    = (const float*)d_in[32];
  const float* pred_b    = (const float*)d_in[33];
  float* out = (float*)d_out;

  // ---- workspace layout (byte offsets), total ~92.2 MB ----
  char* wsb = (char*)d_ws;
  unsigned short* Wsl = (unsigned short*)(wsb);            // 23,592,960 B
  char* slA = wsb + 23592960;                              // 18,874,368
  char* slB = wsb + 42467328;                              // 18,874,368
  char* slC = wsb + 61341696;                              //  9,437,184
  char* slD = wsb + 70778880;                              //  9,437,184
  char* slE = wsb + 80216064;                              //  4,718,592
  char* slF = wsb + 84934656;                              //  4,718,592
  char* slG = wsb + 89653248;                              //  2,359,296
  char* slS = wsb + 92012544;                              //  ~208,896

  float* aff      = (float*)slA;
  float* fusion   = (float*)slB;
  float* partial  = (float*)slC;
  unsigned short* qf8t    = (unsigned short*)slC;
  unsigned short* x8      = (unsigned short*)slC;
  unsigned short* fusionp = (unsigned short*)slD;
  unsigned short* s8      = (unsigned short*)slD;
  unsigned short* dec     = (unsigned short*)slE;
  unsigned short* t1_8    = (unsigned short*)slE;
  unsigned short* t1      = (unsigned short*)slF;
  unsigned short* t2      = (unsigned short*)(slF + 2359296);
  unsigned short* t2_8    = (unsigned short*)slF;
  unsigned short* mbuf    = (unsigned short*)slG;
  unsigned short* x16     = (unsigned short*)slG;
  unsigned short* qf4t    = (unsigned short*)slA;
  unsigned short* t1_4    = (unsigned short*)slA;
  unsigned short* s4      = (unsigned short*)slB;
  float* asq    = (float*)slS;
  float* colsum = (float*)(slS + 27648);
  float* poolb  = (float*)(slS + 36864);
  float* l4     = (float*)(slS + 61440);

  const float scale = 0.04419417382415922f;   // 1/sqrt(512)

  // ---- affinity pipeline (fp32), fusion stored NHWC [b][n][1536] ----
  const float* banksK[3] = {mk16, firstk, adjk};
  const float* banksV[3] = {mv16, firstv, adfv};
  for (int bank = 0; bank < 3; ++bank) {
    asq_k<<<27, 256, 0, stream>>>(banksK[bank], asq);
    gemm64_k<false, 1><<<dim3(27 * 9, 4), 256, 0, stream>>>(
        banksK[bank], qk16, aff, 512, THW, HW16, HW16, 9,
        (size_t)512 * THW, (size_t)512 * HW16, (size_t)THW * HW16,
        asq, scale, nullptr, 0);
    softmax_k<<<dim3(36, 4), 256, 0, stream>>>(aff, colsum);
    gemm64_k<true, 2><<<dim3(8 * 9, 4), 256, 0, stream>>>(
        banksV[bank], aff, fusion, THW, THW, HW16, 1536, 9,
        (size_t)512 * THW, (size_t)THW * HW16, (size_t)HW16 * 1536,
        nullptr, 0.f, colsum, bank * 512);
  }

  pool_k<<<dim3(12, 4), 128, 0, stream>>>(fusion, poolb);
  fusionp_k<<<(3538944 + 255) / 256, 256, 0, stream>>>(fusion, poolb, fusionp, 3538944);

  // ---- mask conv (1536->512 @24x24, sigmoid), split-K=2 ----
  wrep_k<<<(7077888 + 255) / 256, 256, 0, stream>>>(mask_w, Wsl, 512, 1536, 7077888);
  convmf_k<false, 0, true, false><<<dim3(9, 8, 8), 256, 0, stream>>>(
      fusionp, Wsl, nullptr, nullptr, nullptr, partial, 1536, 512, 24, 24, 768);
  skred_k<1, false><<<(1179648 + 255) / 256, 256, 0, stream>>>(
      partial, mask_b, nullptr, mbuf, 512, 1179648);

  decodes_k<<<(2359296 + 255) / 256, 256, 0, stream>>>(fusion, mbuf, qv16, dec);

  // ---- cmp resblock (24x24), split-K=2 ----
  wrep_k<<<(4718592 + 255) / 256, 256, 0, stream>>>(cmp_c1_w, Wsl, 512, 1024, 4718592);
  wrep_k<<<(2359296 + 255) / 256, 256, 0, stream>>>(cmp_c2_w, Wsl + 4718592, 512, 512, 2359296);
  wrep_k<<<(4718592 + 255) / 256, 256, 0, stream>>>(cmp_ds_w, Wsl + 7077888, 512, 1024, 4718592);
  convmf_k<true, 0, true, false><<<dim3(9, 8, 8), 256, 0, stream>>>(
      dec, Wsl, nullptr, nullptr, nullptr, partial, 1024, 512, 24, 24, 512);
  skred_k<0, false><<<(1179648 + 255) / 256, 256, 0, stream>>>(
      partial, cmp_c1_b, nullptr, t1, 512, 1179648);
  convmf_k<true, 0, true, false><<<dim3(9, 8, 8), 256, 0, stream>>>(
      t1, Wsl + 4718592, nullptr, nullptr, nullptr, partial, 512, 512, 24, 24, 256);
  skred_k<0, false><<<(1179648 + 255) / 256, 256, 0, stream>>>(
      partial, cmp_c2_b, nullptr, t2, 512, 1179648);
  convmf_k<false, 0, true, false><<<dim3(9, 8, 8), 256, 0, stream>>>(
      dec, Wsl + 7077888, nullptr, nullptr, nullptr, partial, 1024, 512, 24, 24, 512);
  skred_k<0, true><<<(1179648 + 255) / 256, 256, 0, stream>>>(
      partial, cmp_ds_b, t2, x16, 512, 1179648);

  // ---- u1 stage (48x48) ----
  tr_k<<<dim3(72, 16, 4), 256, 0, stream>>>(qf8, qf8t, 512, 2304);
  wrep_k<<<(2359296 + 255) / 256, 256, 0, stream>>>(u1_skip_w, Wsl, 512, 512, 2359296);
  wrep_k<<<(1179648 + 255) / 256, 256, 0, stream>>>(u1_c1_w, Wsl + 2359296, 256, 512, 1179648);
  wrep_k<<<(589824 + 255) / 256, 256, 0, stream>>>(u1_c2_w, Wsl + 3538944, 256, 256, 589824);
  wrep_k<<<(1179648 + 255) / 256, 256, 0, stream>>>(u1_ds_w, Wsl + 4128768, 256, 512, 1179648);
  convmf_k<false, 0, false, false><<<dim3(36, 8, 4), 256, 0, stream>>>(
      qf8t, Wsl, u1_skip_b, nullptr, s8, nullptr, 512, 512, 48, 48, 512);
  up2add_k<<<(4718592 + 255) / 256, 256, 0, stream>>>(s8, x16, 48, 48, 512, 4718592);
  convmf_k<true, 0, false, false><<<dim3(36, 4, 4), 256, 0, stream>>>(
      s8, Wsl + 2359296, u1_c1_b, nullptr, t1_8, nullptr, 512, 256, 48, 48, 512);
  convmf_k<true, 0, false, false><<<dim3(36, 4, 4), 256, 0, stream>>>(
      t1_8, Wsl + 3538944, u1_c2_b, nullptr, t2_8, nullptr, 256, 256, 48, 48, 256);
  convmf_k<false, 0, false, true><<<dim3(36, 4, 4), 256, 0, stream>>>(
      s8, Wsl + 4128768, u1_ds_b, t2_8, x8, nullptr, 512, 256, 48, 48, 512);

  // ---- u2 stage (96x96) ----
  tr_k<<<dim3(288, 8, 4), 256, 0, stream>>>(qf4, qf4t, 256, 9216);
  wrep_k<<<(589824 + 255) / 256, 256, 0, stream>>>(u2_skip_w, Wsl, 256, 256, 589824);
  wrep_k<<<(589824 + 255) / 256, 256, 0, stream>>>(u2_c1_w, Wsl + 589824, 256, 256, 589824);
  wrep_k<<<(589824 + 255) / 256, 256, 0, stream>>>(u2_c2_w, Wsl + 1179648, 256, 256, 589824);
  convmf_k<false, 0, false, false><<<dim3(144, 4, 4), 256, 0, stream>>>(
      qf4t, Wsl, u2_skip_b, nullptr, s4, nullptr, 256, 256, 96, 96, 256);
  up2add_k<<<(9437184 + 255) / 256, 256, 0, stream>>>(s4, x8, 96, 96, 256, 9437184);
  convmf_k<true, 0, false, false><<<dim3(144, 4, 4), 256, 0, stream>>>(
      s4, Wsl + 589824, u2_c1_b, nullptr, t1_4, nullptr, 256, 256, 96, 96, 256);
  convmf_k<true, 0, false, true><<<dim3(144, 4, 4), 256, 0, stream>>>(
      t1_4, Wsl + 1179648, u2_c2_b, s4, s4, nullptr, 256, 256, 96, 96, 256);

  pred_k<<<9216, 256, 0, stream>>>(s4, pred_w, pred_b, l4);
  final_k<<<(589824 + 255) / 256, 256, 0, stream>>>(l4, out);
}

// Round 3
// 1489.694 us; speedup vs baseline: 6.7175x; 1.5445x over previous
//
#include <hip/hip_runtime.h>
#include <math.h>

// ---------------------------------------------------------------------------
// STCN forward. Round 3: affinity/readout also bf16 MFMA (split-K readout),
// row-contiguous fused softmax. Convs unchanged from round 2.
// ---------------------------------------------------------------------------

static constexpr int THW  = 1728;
static constexpr int HW16 = 576;

typedef __attribute__((ext_vector_type(8))) short bf16x8;
typedef __attribute__((ext_vector_type(4))) float f32x4;
typedef unsigned int uint;

__device__ __forceinline__ float sigmf(float x) { return 1.f / (1.f + expf(-x)); }

__device__ __forceinline__ float bf2f(unsigned short u) {
  union { float f; uint i; } x; x.i = ((uint)u) << 16; return x.f;
}
__device__ __forceinline__ unsigned short f2bf(float f) {
  union { float f; uint i; } x; x.f = f;
  uint r = x.i + 0x7fffu + ((x.i >> 16) & 1u);
  return (unsigned short)(r >> 16);
}
__device__ __forceinline__ uint relu2(uint x) {
  uint lo = (x & 0x8000u) ? 0u : (x & 0xFFFFu);
  uint hi = (x & 0x80000000u) ? 0u : (x & 0xFFFF0000u);
  return lo | hi;
}
__device__ __forceinline__ bf16x8 lds_ld8(const unsigned short* p) {
  union { uint2 u2[2]; bf16x8 v; } x;
  x.u2[0] = *(const uint2*)(p);
  x.u2[1] = *(const uint2*)(p + 4);
  return x.v;
}

// ---------------- NCHW fp32 -> NHWC bf16 transpose -------------------------
__global__ __launch_bounds__(256) void tr_k(const float* __restrict__ in,
                                            unsigned short* __restrict__ out,
                                            int C, int HW) {
  __shared__ float t[32][33];
  int p0 = blockIdx.x << 5, c0 = blockIdx.y << 5, b = blockIdx.z;
  int tx = threadIdx.x & 31, ty = threadIdx.x >> 5;
  const float* ib = in + (size_t)b * C * HW;
  #pragma unroll
  for (int e = 0; e < 4; ++e)
    t[ty + e * 8][tx] = ib[(size_t)(c0 + ty + e * 8) * HW + p0 + tx];
  __syncthreads();
  unsigned short* ob = out + (size_t)b * C * HW;
  #pragma unroll
  for (int e = 0; e < 4; ++e)
    ob[(size_t)(p0 + ty + e * 8) * C + c0 + tx] = f2bf(t[tx][ty + e * 8]);
}

// ---------------- elementwise fp32 -> bf16 ---------------------------------
__global__ __launch_bounds__(256) void cvt_k(const float* __restrict__ in,
                                             unsigned short* __restrict__ o, int n) {
  int i = blockIdx.x * 256 + threadIdx.x;
  if (i < n) o[i] = f2bf(in[i]);
}

// ---------------- asq[b][t] = sum_c mkT[b][t][c]^2  (bf16 rows) ------------
__global__ __launch_bounds__(256) void asq2_k(const unsigned short* __restrict__ mkT,
                                              float* __restrict__ asq) {
  int row = blockIdx.x * 4 + (threadIdx.x >> 6);   // 4*1728 rows
  int lane = threadIdx.x & 63;
  const unsigned short* p = mkT + (size_t)row * 512;
  float s = 0.f;
  #pragma unroll
  for (int i = 0; i < 8; ++i) { float v = bf2f(p[lane + (i << 6)]); s += v * v; }
  #pragma unroll
  for (int m = 32; m > 0; m >>= 1) s += __shfl_xor(s, m);
  if (lane == 0) asq[row] = s;
}

// ---------------- bf16 MFMA GEMM: A[M][K], B[N][K], both k-major -----------
// 64x64 tile, 4 waves (2x2 of 32x32), k-chunk 32.
// EPI==1: C^T store: C[b][n][m] = (2*acc - asq[b*1728+m]) * scale  (fp32)
// EPI==2: partial store: C[(split*4+b)][n][m] = acc                (fp32)
template<int EPI, int SPLIT>
__global__ __launch_bounds__(256) void mfgemm_k(
    const unsigned short* __restrict__ A, const unsigned short* __restrict__ Bm,
    float* __restrict__ C, const float* __restrict__ asq,
    int K, int ldc, int Nt, size_t aBS, size_t bBS, size_t cBS, float scale)
{
  const int by = blockIdx.y;
  const int b = by & 3, split = by >> 2;
  const int mt = blockIdx.x / Nt, nt = blockIdx.x - mt * Nt;
  const int m0 = mt << 6, n0 = nt << 6;
  const unsigned short* Ab = A + (size_t)b * aBS + (size_t)m0 * K;
  const unsigned short* Bb = Bm + (size_t)b * bBS + (size_t)n0 * K;
  __shared__ unsigned short sA[64][36];
  __shared__ unsigned short sB[64][36];
  const int tid = threadIdx.x;
  const int lane = tid & 63, wv = tid >> 6;
  const int mS = (wv >> 1) << 5, nS = (wv & 1) << 5;
  const int l15 = lane & 15, lq = lane >> 4;
  const int srow = tid >> 2, scol = (tid & 3) << 3;
  f32x4 acc[2][2];
  #pragma unroll
  for (int i = 0; i < 2; ++i)
    #pragma unroll
    for (int j = 0; j < 2; ++j) acc[i][j] = (f32x4){0.f, 0.f, 0.f, 0.f};
  const int Kper = K / SPLIT;
  const int kLo = split * Kper, kHi = kLo + Kper;
  for (int k0 = kLo; k0 < kHi; k0 += 32) {
    uint4 va = *(const uint4*)(Ab + (size_t)srow * K + k0 + scol);
    uint4 vb = *(const uint4*)(Bb + (size_t)srow * K + k0 + scol);
    *(uint2*)&sA[srow][scol]     = make_uint2(va.x, va.y);
    *(uint2*)&sA[srow][scol + 4] = make_uint2(va.z, va.w);
    *(uint2*)&sB[srow][scol]     = make_uint2(vb.x, vb.y);
    *(uint2*)&sB[srow][scol + 4] = make_uint2(vb.z, vb.w);
    __syncthreads();
    bf16x8 a0 = lds_ld8(&sA[mS + l15][lq << 3]);
    bf16x8 a1 = lds_ld8(&sA[mS + 16 + l15][lq << 3]);
    bf16x8 b0 = lds_ld8(&sB[nS + l15][lq << 3]);
    bf16x8 b1 = lds_ld8(&sB[nS + 16 + l15][lq << 3]);
    acc[0][0] = __builtin_amdgcn_mfma_f32_16x16x32_bf16(a0, b0, acc[0][0], 0, 0, 0);
    acc[0][1] = __builtin_amdgcn_mfma_f32_16x16x32_bf16(a0, b1, acc[0][1], 0, 0, 0);
    acc[1][0] = __builtin_amdgcn_mfma_f32_16x16x32_bf16(a1, b0, acc[1][0], 0, 0, 0);
    acc[1][1] = __builtin_amdgcn_mfma_f32_16x16x32_bf16(a1, b1, acc[1][1], 0, 0, 0);
    __syncthreads();
  }
  float* Cb = C + (size_t)(EPI == 2 ? (split * 4 + b) : b) * cBS;
  #pragma unroll
  for (int i = 0; i < 2; ++i) {
    const int mrow = m0 + mS + i * 16 + (lq << 2);
    #pragma unroll
    for (int j = 0; j < 2; ++j) {
      const int n = n0 + nS + j * 16 + l15;
      float4 v;
      if constexpr (EPI == 1) {
        float4 aq = *(const float4*)(asq + b * THW + mrow);
        v.x = (2.f * acc[i][j][0] - aq.x) * scale;
        v.y = (2.f * acc[i][j][1] - aq.y) * scale;
        v.z = (2.f * acc[i][j][2] - aq.z) * scale;
        v.w = (2.f * acc[i][j][3] - aq.w) * scale;
      } else {
        v.x = acc[i][j][0]; v.y = acc[i][j][1];
        v.z = acc[i][j][2]; v.w = acc[i][j][3];
      }
      *(float4*)(Cb + (size_t)n * ldc + mrow) = v;
    }
  }
}

// ---------------- row softmax: S^T[row][1728] fp32 -> P bf16 normalized ----
__global__ __launch_bounds__(256) void softmaxT_k(const float* __restrict__ S,
                                                  unsigned short* __restrict__ P) {
  int row = blockIdx.x * 4 + (threadIdx.x >> 6);   // 2304 rows
  int lane = threadIdx.x & 63;
  const float* sp = S + (size_t)row * THW;
  float v[27];
  float mx = -3.0e38f;
  #pragma unroll
  for (int i = 0; i < 27; ++i) { v[i] = sp[lane + (i << 6)]; mx = fmaxf(mx, v[i]); }
  #pragma unroll
  for (int m = 32; m > 0; m >>= 1) mx = fmaxf(mx, __shfl_xor(mx, m));
  float sum = 0.f;
  #pragma unroll
  for (int i = 0; i < 27; ++i) { v[i] = expf(v[i] - mx); sum += v[i]; }
  #pragma unroll
  for (int m = 32; m > 0; m >>= 1) sum += __shfl_xor(sum, m);
  float inv = 1.f / sum;
  unsigned short* pp = P + (size_t)row * THW;
  #pragma unroll
  for (int i = 0; i < 27; ++i) pp[lane + (i << 6)] = f2bf(v[i] * inv);
}

// ---------------- readout split-K=3 reduce -> fusion NHWC ------------------
__global__ __launch_bounds__(256) void skred3_k(const float* __restrict__ part,
                                                float* __restrict__ fusion, int cOff) {
  int i = blockIdx.x * 256 + threadIdx.x;
  if (i >= 4 * HW16 * 512) return;
  const int N = 4 * HW16 * 512;
  float v = part[i] + part[i + N] + part[i + 2 * N];
  int c = i & 511; int t = i >> 9; int n = t % HW16; int b = t / HW16;
  fusion[((size_t)b * HW16 + n) * 1536 + cOff + c] = v;
}

// ---------------- pool over pixels of NHWC fusion --------------------------
__global__ __launch_bounds__(128) void pool_k(const float* __restrict__ f,
                                              float* __restrict__ pool) {
  int b = blockIdx.y, c = blockIdx.x * 128 + threadIdx.x;
  const float* p = f + (size_t)b * HW16 * 1536 + c;
  float s = 0.f;
  for (int n = 0; n < HW16; ++n) s += p[(size_t)n * 1536];
  pool[b * 1536 + c] = s * (1.f / 576.f);
}

// fusionp = bf16(fusion + pool), NHWC
__global__ __launch_bounds__(256) void fusionp_k(const float* __restrict__ f,
                                                 const float* __restrict__ pool,
                                                 unsigned short* __restrict__ o, int total) {
  int i = blockIdx.x * 256 + threadIdx.x;
  if (i >= total) return;
  int c = i % 1536; int b = i / (HW16 * 1536);
  o[i] = f2bf(f[i] + pool[b * 1536 + c]);
}

// dec NHWC bf16 [b][n][1024]: c<512 -> (l+g+a)*(m+1); else qv16 (CHW fp32)
__global__ __launch_bounds__(256) void decodes_k(const float* __restrict__ fusion,
                                                 const unsigned short* __restrict__ m,
                                                 const float* __restrict__ qv,
                                                 unsigned short* __restrict__ o) {
  int i = blockIdx.x * 256 + threadIdx.x;
  if (i >= 4 * HW16 * 1024) return;
  int c = i & 1023; int t = i >> 10; int n = t % HW16; int b = t / HW16;
  float v;
  if (c < 512) {
    const float* f = fusion + ((size_t)b * HW16 + n) * 1536;
    float s3 = f[c] + f[c + 512] + f[c + 1024];
    float mf = bf2f(m[((size_t)b * HW16 + n) * 512 + c]);
    v = s3 * (mf + 1.f);
  } else {
    v = qv[((size_t)b * 512 + (c - 512)) * HW16 + n];
  }
  o[i] = f2bf(v);
}

// ---------------- weight repack OIHW fp32 -> [tap][co][ci] bf16 ------------
__global__ __launch_bounds__(256) void wrep_k(const float* __restrict__ w,
                                              unsigned short* __restrict__ o,
                                              int Cout, int Cin, int total) {
  int i = blockIdx.x * 256 + threadIdx.x;
  if (i >= total) return;
  int ci = i % Cin; int t = i / Cin; int co = t % Cout; int tap = t / Cout;
  o[i] = f2bf(w[((size_t)co * Cin + ci) * 9 + tap]);
}

// ---------------- MFMA conv3x3, NHWC bf16 ----------------------------------
template<bool RELU_IN, int ACT, bool SPLITK, bool HAS_ADD>
__global__ __launch_bounds__(256) void convmf_k(
    const unsigned short* __restrict__ in, const unsigned short* __restrict__ W2,
    const float* __restrict__ bias, const unsigned short* __restrict__ add,
    unsigned short* __restrict__ outb, float* __restrict__ outp,
    int Cin, int Cout, int H, int W, int ciPer)
{
  const int tilesX = W >> 3;
  const int tx0 = (blockIdx.x % tilesX) << 3;
  const int ty0 = (blockIdx.x / tilesX) << 3;
  const int co0 = blockIdx.y << 6;
  const int b = blockIdx.z & 3;
  const int split = blockIdx.z >> 2;
  const int HWp = H * W;
  __shared__ unsigned short sA[9][64][36];
  __shared__ unsigned short sB[100][36];
  const int tid = threadIdx.x;
  const int lane = tid & 63, wv = tid >> 6;
  const int cS = (wv >> 1) << 5;
  const int nS = (wv & 1) << 5;
  const int l15 = lane & 15, lq = lane >> 4;
  int hp0[2], gp[2];
  #pragma unroll
  for (int j = 0; j < 2; ++j) {
    int n = nS + j * 16 + l15;
    int py = n >> 3, px = n & 7;
    hp0[j] = py * 10 + px;
    gp[j] = (ty0 + py) * W + tx0 + px;
  }
  f32x4 acc[2][2];
  #pragma unroll
  for (int i = 0; i < 2; ++i)
    #pragma unroll
    for (int j = 0; j < 2; ++j) acc[i][j] = (f32x4){0.f, 0.f, 0.f, 0.f};
  const size_t inBase = (size_t)b * HWp * Cin;
  const int kLo = split * ciPer, kHi = kLo + ciPer;
  const int sco = tid >> 2;
  const int sc8 = (tid & 3) << 3;
  for (int k0 = kLo; k0 < kHi; k0 += 32) {
    #pragma unroll
    for (int tap = 0; tap < 9; ++tap) {
      const uint4 v = *(const uint4*)(W2 + ((size_t)(tap * Cout + co0 + sco) * Cin + k0 + sc8));
      *(uint2*)&sA[tap][sco][sc8]     = make_uint2(v.x, v.y);
      *(uint2*)&sA[tap][sco][sc8 + 4] = make_uint2(v.z, v.w);
    }
    #pragma unroll
    for (int e = 0; e < 2; ++e) {
      int idx = tid + (e << 8);
      if (idx < 400) {
        int hp = idx >> 2, c8 = (idx & 3) << 3;
        int hy = ty0 + (hp / 10) - 1;
        int hx = tx0 + (hp % 10) - 1;
        uint4 v = make_uint4(0u, 0u, 0u, 0u);
        if (hy >= 0 && hy < H && hx >= 0 && hx < W)
          v = *(const uint4*)(in + inBase + (size_t)(hy * W + hx) * Cin + k0 + c8);
        if (RELU_IN) { v.x = relu2(v.x); v.y = relu2(v.y); v.z = relu2(v.z); v.w = relu2(v.w); }
        *(uint2*)&sB[hp][c8]     = make_uint2(v.x, v.y);
        *(uint2*)&sB[hp][c8 + 4] = make_uint2(v.z, v.w);
      }
    }
    __syncthreads();
    const int DT[9] = {0, 1, 2, 10, 11, 12, 20, 21, 22};
    #pragma unroll
    for (int tap = 0; tap < 9; ++tap) {
      bf16x8 a0 = lds_ld8(&sA[tap][cS + l15][lq << 3]);
      bf16x8 a1 = lds_ld8(&sA[tap][cS + 16 + l15][lq << 3]);
      bf16x8 b0 = lds_ld8(&sB[hp0[0] + DT[tap]][lq << 3]);
      bf16x8 b1 = lds_ld8(&sB[hp0[1] + DT[tap]][lq << 3]);
      acc[0][0] = __builtin_amdgcn_mfma_f32_16x16x32_bf16(a0, b0, acc[0][0], 0, 0, 0);
      acc[0][1] = __builtin_amdgcn_mfma_f32_16x16x32_bf16(a0, b1, acc[0][1], 0, 0, 0);
      acc[1][0] = __builtin_amdgcn_mfma_f32_16x16x32_bf16(a1, b0, acc[1][0], 0, 0, 0);
      acc[1][1] = __builtin_amdgcn_mfma_f32_16x16x32_bf16(a1, b1, acc[1][1], 0, 0, 0);
    }
    __syncthreads();
  }
  #pragma unroll
  for (int i = 0; i < 2; ++i) {
    const int coB = co0 + cS + i * 16 + (lq << 2);
    #pragma unroll
    for (int j = 0; j < 2; ++j) {
      if constexpr (SPLITK) {
        float* dst = outp + ((size_t)(split * 4 + b) * HWp + gp[j]) * Cout + coB;
        float4 v; v.x = acc[i][j][0]; v.y = acc[i][j][1]; v.z = acc[i][j][2]; v.w = acc[i][j][3];
        *(float4*)dst = v;
      } else {
        float4 bv = *(const float4*)(bias + coB);
        float v0 = acc[i][j][0] + bv.x, v1 = acc[i][j][1] + bv.y;
        float v2 = acc[i][j][2] + bv.z, v3 = acc[i][j][3] + bv.w;
        const size_t base = ((size_t)b * HWp + gp[j]) * Cout + coB;
        if constexpr (HAS_ADD) {
          ushort4 a4 = *(const ushort4*)(add + base);
          v0 += bf2f(a4.x); v1 += bf2f(a4.y); v2 += bf2f(a4.z); v3 += bf2f(a4.w);
        }
        if constexpr (ACT == 1) { v0 = sigmf(v0); v1 = sigmf(v1); v2 = sigmf(v2); v3 = sigmf(v3); }
        ushort4 o; o.x = f2bf(v0); o.y = f2bf(v1); o.z = f2bf(v2); o.w = f2bf(v3);
        *(ushort4*)(outb + base) = o;
      }
    }
  }
}

// ---------------- split-K reduce + epilogue --------------------------------
template<int ACT, bool HAS_ADD>
__global__ __launch_bounds__(256) void skred_k(
    const float* __restrict__ part, const float* __restrict__ bias,
    const unsigned short* __restrict__ add, unsigned short* __restrict__ out,
    int Cout, int n)
{
  int i = blockIdx.x * 256 + threadIdx.x;
  if (i >= n) return;
  float v = part[i] + part[i + n] + bias[i % Cout];
  if (HAS_ADD) v += bf2f(add[i]);
  if (ACT == 1) v = sigmf(v);
  out[i] = f2bf(v);
}

// ---------------- s += bilinear 2x upsample (NHWC bf16) --------------------
__global__ __launch_bounds__(256) void up2add_k(unsigned short* __restrict__ s,
                                                const unsigned short* __restrict__ x,
                                                int OH, int OW, int C, int total) {
  int i = blockIdx.x * 256 + threadIdx.x;
  if (i >= total) return;
  int c = i % C; int op = i / C;
  int ox = op % OW; int t = op / OW; int oy = t % OH; int b = t / OH;
  int IH = OH >> 1, IW = OW >> 1;
  const unsigned short* xp = x + ((size_t)b * IH * IW) * C + c;
  float uy = 0.5f * oy - 0.25f;
  float ux = 0.5f * ox - 0.25f;
  int y0 = (int)floorf(uy); float fy = uy - (float)y0;
  int x0 = (int)floorf(ux); float fx = ux - (float)x0;
  int y0c = y0 < 0 ? 0 : y0; int y1c = (y0 + 1 >= IH) ? IH - 1 : y0 + 1;
  int x0c = x0 < 0 ? 0 : x0; int x1c = (x0 + 1 >= IW) ? IW - 1 : x0 + 1;
  float v00 = bf2f(xp[(size_t)(y0c * IW + x0c) * C]);
  float v01 = bf2f(xp[(size_t)(y0c * IW + x1c) * C]);
  float v10 = bf2f(xp[(size_t)(y1c * IW + x0c) * C]);
  float v11 = bf2f(xp[(size_t)(y1c * IW + x1c) * C]);
  float r = (1.f - fy) * ((1.f - fx) * v00 + fx * v01)
          + fy * ((1.f - fx) * v10 + fx * v11);
  s[i] = f2bf(bf2f(s[i]) + r);
}

// ---------------- pred head: 256->1 conv, relu-in, NHWC bf16 ---------------
__global__ __launch_bounds__(256) void pred_k(const unsigned short* __restrict__ in,
                                              const float* __restrict__ w,
                                              const float* __restrict__ bias,
                                              float* __restrict__ l4) {
  __shared__ float sw[9][256];
  for (int idx = threadIdx.x; idx < 2304; idx += 256)
    sw[idx % 9][idx / 9] = w[idx];
  __syncthreads();
  int gpix = blockIdx.x * 4 + (threadIdx.x >> 6);
  int b = gpix / 9216, pix = gpix % 9216;
  int py = pix / 96, px = pix % 96;
  int lane = threadIdx.x & 63;
  float acc = 0.f;
  #pragma unroll
  for (int ky = 0; ky < 3; ++ky) {
    int gy = py + ky - 1; if (gy < 0 || gy > 95) continue;
    #pragma unroll
    for (int kx = 0; kx < 3; ++kx) {
      int gx = px + kx - 1; if (gx < 0 || gx > 95) continue;
      const unsigned short* ip = in + ((size_t)b * 9216 + gy * 96 + gx) * 256;
      const float* wp = sw[ky * 3 + kx];
      #pragma unroll
      for (int cq = 0; cq < 4; ++cq) {
        int c = lane + (cq << 6);
        acc += fmaxf(bf2f(ip[c]), 0.f) * wp[c];
      }
    }
  }
  #pragma unroll
  for (int off = 32; off > 0; off >>= 1) acc += __shfl_down(acc, off);
  if (lane == 0) l4[gpix] = acc + bias[0];
}

// ---------------- bilinear 4x + sigmoid/aggregate/output -------------------
__global__ __launch_bounds__(256) void final_k(const float* __restrict__ l4,
                                               float* __restrict__ out) {
  int i = blockIdx.x * 256 + threadIdx.x;
  if (i >= 4 * 384 * 384) return;
  int ox = i % 384; int t = i / 384; int oy = t % 384; int b = t / 384;
  const float* lp = l4 + (size_t)b * 96 * 96;
  float uy = 0.25f * oy - 0.375f;
  float ux = 0.25f * ox - 0.375f;
  int y0 = (int)floorf(uy); float fy = uy - (float)y0;
  int x0 = (int)floorf(ux); float fx = ux - (float)x0;
  int y0c = y0 < 0 ? 0 : y0; int y1c = (y0 + 1 > 95) ? 95 : y0 + 1;
  int x0c = x0 < 0 ? 0 : x0; int x1c = (x0 + 1 > 95) ? 95 : x0 + 1;
  float l = (1.f - fy) * ((1.f - fx) * lp[y0c * 96 + x0c] + fx * lp[y0c * 96 + x1c])
          + fy * ((1.f - fx) * lp[y1c * 96 + x0c] + fx * lp[y1c * 96 + x1c]);
  float p  = 1.f / (1.f + expf(-l));
  float p1 = fminf(fmaxf(p, 1e-7f), 1.f - 1e-7f);
  float p0 = fminf(fmaxf(1.f - p, 1e-7f), 1.f - 1e-7f);
  float L0 = logf(p0 / (1.f - p0));
  float L1 = logf(p1 / (1.f - p1));
  int sp = oy * 384 + ox;
  out[(size_t)(b * 2) * 147456 + sp] = L0;
  out[(size_t)(b * 2 + 1) * 147456 + sp] = L1;
  out[(size_t)1179648 + (size_t)b * 147456 + sp] = 1.f / (1.f + expf(L0 - L1));
}

// ---------------------------------------------------------------------------
extern "C" void kernel_launch(void* const* d_in, const int* in_sizes, int n_in,
                              void* d_out, int out_size, void* d_ws, size_t ws_size,
                              hipStream_t stream)
{
  (void)in_sizes; (void)n_in; (void)out_size; (void)ws_size;
  const float* qk16   = (const float*)d_in[0];
  const float* qv16   = (const float*)d_in[1];
  const float* qf8    = (const float*)d_in[2];
  const float* qf4    = (const float*)d_in[3];
  const float* mk16   = (const float*)d_in[4];
  const float* mv16   = (const float*)d_in[5];
  const float* firstk = (const float*)d_in[6];
  const float* firstv = (const float*)d_in[7];
  const float* adjk   = (const float*)d_in[8];
  const float* adfv   = (const float*)d_in[9];
  const float* mask_w   = (const float*)d_in[10];
  const float* mask_b   = (const float*)d_in[11];
  const float* cmp_ds_w = (const float*)d_in[12];
  const float* cmp_ds_b = (const float*)d_in[13];
  const float* cmp_c1_w = (const float*)d_in[14];
  const float* cmp_c1_b = (const float*)d_in[15];
  const float* cmp_c2_w = (const float*)d_in[16];
  const float* cmp_c2_b = (const float*)d_in[17];
  const float* u1_skip_w = (const float*)d_in[18];
  const float* u1_skip_b = (const float*)d_in[19];
  const float* u1_ds_w   = (const float*)d_in[20];
  const float* u1_ds_b   = (const float*)d_in[21];
  const float* u1_c1_w   = (const float*)d_in[22];
  const float* u1_c1_b   = (const float*)d_in[23];
  const float* u1_c2_w   = (const float*)d_in[24];
  const float* u1_c2_b   = (const float*)d_in[25];
  const float* u2_skip_w = (const float*)d_in[26];
  const float* u2_skip_b = (const float*)d_in[27];
  const float* u2_c1_w   = (const float*)d_in[28];
  const float* u2_c1_b   = (const float*)d_in[29];
  const float* u2_c2_w   = (const float*)d_in[30];
  const float* u2_c2_b   = (const float*)d_in[31];
  const float* pred_w    = (const float*)d_in[32];
  const float* pred_b    = (const float*)d_in[33];
  float* out = (float*)d_out;

  // ---- workspace layout (byte offsets), ~92.2 MB ----
  char* wsb = (char*)d_ws;
  unsigned short* Wsl = (unsigned short*)(wsb);            // 23,592,960 B
  char* slA = wsb + 23592960;                              // 18,874,368
  char* slB = wsb + 42467328;                              // 18,874,368
  char* slC = wsb + 61341696;                              //  9,437,184
  char* slD = wsb + 70778880;                              //  9,437,184
  char* slE = wsb + 80216064;                              //  4,718,592
  char* slF = wsb + 84934656;                              //  4,718,592
  char* slG = wsb + 89653248;                              //  2,359,296
  char* slS = wsb + 92012544;                              //  ~208,896

  // affinity-phase aliases
  unsigned short* mkT = Wsl;                               // 7,077,888 B
  unsigned short* mvb = Wsl + 3538944;                     // 7,077,888 B
  unsigned short* qkT = Wsl + 7077888;                     // 2,359,296 B
  float* aff      = (float*)slA;                           // 15,925,248 B (S^T)
  float* rpart    = (float*)slA;                           // 14,155,776 B (after aff dead)
  unsigned short* Pmat = (unsigned short*)slC;             // 7,962,624 B
  float* fusion   = (float*)slB;
  // conv-phase aliases
  float* partial  = (float*)slC;
  unsigned short* qf8t    = (unsigned short*)slC;
  unsigned short* x8      = (unsigned short*)slC;
  unsigned short* fusionp = (unsigned short*)slD;
  unsigned short* s8      = (unsigned short*)slD;
  unsigned short* dec     = (unsigned short*)slE;
  unsigned short* t1_8    = (unsigned short*)slE;
  unsigned short* t1      = (unsigned short*)slF;
  unsigned short* t2      = (unsigned short*)(slF + 2359296);
  unsigned short* t2_8    = (unsigned short*)slF;
  unsigned short* mbuf    = (unsigned short*)slG;
  unsigned short* x16     = (unsigned short*)slG;
  unsigned short* qf4t    = (unsigned short*)slA;
  unsigned short* t1_4    = (unsigned short*)slA;
  unsigned short* s4      = (unsigned short*)slB;
  float* asqb   = (float*)slS;                             // 27,648 B
  float* poolb  = (float*)(slS + 36864);
  float* l4     = (float*)(slS + 61440);

  const float scale = 0.04419417382415922f;   // 1/sqrt(512)

  // ---- affinity pipeline (bf16 MFMA), fusion NHWC [b][n][1536] fp32 ----
  tr_k<<<dim3(18, 16, 4), 256, 0, stream>>>(qk16, qkT, 512, 576);
  const float* banksK[3] = {mk16, firstk, adjk};
  const float* banksV[3] = {mv16, firstv, adfv};
  for (int bank = 0; bank < 3; ++bank) {
    tr_k<<<dim3(54, 16, 4), 256, 0, stream>>>(banksK[bank], mkT, 512, 1728);
    asq2_k<<<1728, 256, 0, stream>>>(mkT, asqb);
    // S^T[b][n][t] = (2*mkT.qkT^T - asq)*scale : M=1728(t), N=576(n), K=512
    mfgemm_k<1, 1><<<dim3(243, 4), 256, 0, stream>>>(
        mkT, qkT, aff, asqb, 512, THW, 9,
        (size_t)THW * 512, (size_t)HW16 * 512, (size_t)HW16 * THW, scale);
    softmaxT_k<<<576, 256, 0, stream>>>(aff, Pmat);
    cvt_k<<<(3538944 + 255) / 256, 256, 0, stream>>>(banksV[bank], mvb, 3538944);
    // readout: M=512(c), N=576(n), K=1728(t), split-K=3 -> rpart
    mfgemm_k<2, 3><<<dim3(72, 12), 256, 0, stream>>>(
        mvb, Pmat, rpart, nullptr, 1728, 512, 9,
        (size_t)512 * THW, (size_t)HW16 * THW, (size_t)HW16 * 512, 0.f);
    skred3_k<<<(1179648 + 255) / 256, 256, 0, stream>>>(rpart, fusion, bank * 512);
  }

  pool_k<<<dim3(12, 4), 128, 0, stream>>>(fusion, poolb);
  fusionp_k<<<(3538944 + 255) / 256, 256, 0, stream>>>(fusion, poolb, fusionp, 3538944);

  // ---- mask conv (1536->512 @24x24, sigmoid), split-K=2 ----
  wrep_k<<<(7077888 + 255) / 256, 256, 0, stream>>>(mask_w, Wsl, 512, 1536, 7077888);
  convmf_k<false, 0, true, false><<<dim3(9, 8, 8), 256, 0, stream>>>(
      fusionp, Wsl, nullptr, nullptr, nullptr, partial, 1536, 512, 24, 24, 768);
  skred_k<1, false><<<(1179648 + 255) / 256, 256, 0, stream>>>(
      partial, mask_b, nullptr, mbuf, 512, 1179648);

  decodes_k<<<(2359296 + 255) / 256, 256, 0, stream>>>(fusion, mbuf, qv16, dec);

  // ---- cmp resblock (24x24), split-K=2 ----
  wrep_k<<<(4718592 + 255) / 256, 256, 0, stream>>>(cmp_c1_w, Wsl, 512, 1024, 4718592);
  wrep_k<<<(2359296 + 255) / 256, 256, 0, stream>>>(cmp_c2_w, Wsl + 4718592, 512, 512, 2359296);
  wrep_k<<<(4718592 + 255) / 256, 256, 0, stream>>>(cmp_ds_w, Wsl + 7077888, 512, 1024, 4718592);
  convmf_k<true, 0, true, false><<<dim3(9, 8, 8), 256, 0, stream>>>(
      dec, Wsl, nullptr, nullptr, nullptr, partial, 1024, 512, 24, 24, 512);
  skred_k<0, false><<<(1179648 + 255) / 256, 256, 0, stream>>>(
      partial, cmp_c1_b, nullptr, t1, 512, 1179648);
  convmf_k<true, 0, true, false><<<dim3(9, 8, 8), 256, 0, stream>>>(
      t1, Wsl + 4718592, nullptr, nullptr, nullptr, partial, 512, 512, 24, 24, 256);
  skred_k<0, false><<<(1179648 + 255) / 256, 256, 0, stream>>>(
      partial, cmp_c2_b, nullptr, t2, 512, 1179648);
  convmf_k<false, 0, true, false><<<dim3(9, 8, 8), 256, 0, stream>>>(
      dec, Wsl + 7077888, nullptr, nullptr, nullptr, partial, 1024, 512, 24, 24, 512);
  skred_k<0, true><<<(1179648 + 255) / 256, 256, 0, stream>>>(
      partial, cmp_ds_b, t2, x16, 512, 1179648);

  // ---- u1 stage (48x48) ----
  tr_k<<<dim3(72, 16, 4), 256, 0, stream>>>(qf8, qf8t, 512, 2304);
  wrep_k<<<(2359296 + 255) / 256, 256, 0, stream>>>(u1_skip_w, Wsl, 512, 512, 2359296);
  wrep_k<<<(1179648 + 255) / 256, 256, 0, stream>>>(u1_c1_w, Wsl + 2359296, 256, 512, 1179648);
  wrep_k<<<(589824 + 255) / 256, 256, 0, stream>>>(u1_c2_w, Wsl + 3538944, 256, 256, 589824);
  wrep_k<<<(1179648 + 255) / 256, 256, 0, stream>>>(u1_ds_w, Wsl + 4128768, 256, 512, 1179648);
  convmf_k<false, 0, false, false><<<dim3(36, 8, 4), 256, 0, stream>>>(
      qf8t, Wsl, u1_skip_b, nullptr, s8, nullptr, 512, 512, 48, 48, 512);
  up2add_k<<<(4718592 + 255) / 256, 256, 0, stream>>>(s8, x16, 48, 48, 512, 4718592);
  convmf_k<true, 0, false, false><<<dim3(36, 4, 4), 256, 0, stream>>>(
      s8, Wsl + 2359296, u1_c1_b, nullptr, t1_8, nullptr, 512, 256, 48, 48, 512);
  convmf_k<true, 0, false, false><<<dim3(36, 4, 4), 256, 0, stream>>>(
      t1_8, Wsl + 3538944, u1_c2_b, nullptr, t2_8, nullptr, 256, 256, 48, 48, 256);
  convmf_k<false, 0, false, true><<<dim3(36, 4, 4), 256, 0, stream>>>(
      s8, Wsl + 4128768, u1_ds_b, t2_8, x8, nullptr, 512, 256, 48, 48, 512);

  // ---- u2 stage (96x96) ----
  tr_k<<<dim3(288, 8, 4), 256, 0, stream>>>(qf4, qf4t, 256, 9216);
  wrep_k<<<(589824 + 255) / 256, 256, 0, stream>>>(u2_skip_w, Wsl, 256, 256, 589824);
  wrep_k<<<(589824 + 255) / 256, 256, 0, stream>>>(u2_c1_w, Wsl + 589824, 256, 256, 589824);
  wrep_k<<<(589824 + 255) / 256, 256, 0, stream>>>(u2_c2_w, Wsl + 1179648, 256, 256, 589824);
  convmf_k<false, 0, false, false><<<dim3(144, 4, 4), 256, 0, stream>>>(
      qf4t, Wsl, u2_skip_b, nullptr, s4, nullptr, 256, 256, 96, 96, 256);
  up2add_k<<<(9437184 + 255) / 256, 256, 0, stream>>>(s4, x8, 96, 96, 256, 9437184);
  convmf_k<true, 0, false, false><<<dim3(144, 4, 4), 256, 0, stream>>>(
      s4, Wsl + 589824, u2_c1_b, nullptr, t1_4, nullptr, 256, 256, 96, 96, 256);
  convmf_k<true, 0, false, true><<<dim3(144, 4, 4), 256, 0, stream>>>(
      t1_4, Wsl + 1179648, u2_c2_b, s4, s4, nullptr, 256, 256, 96, 96, 256);

  pred_k<<<9216, 256, 0, stream>>>(s4, pred_w, pred_b, l4);
  final_k<<<(589824 + 255) / 256, 256, 0, stream>>>(l4, out);
}

// Round 4
// 1310.193 us; speedup vs baseline: 7.6378x; 1.1370x over previous
//
#include <hip/hip_runtime.h>
#include <math.h>

// ---------------------------------------------------------------------------
// STCN forward. Round 4: conv = 128co x 128pix MFMA blocks, 64x64 per wave,
// ky-row weight staging, pad-40 LDS (16B-aligned b128 reads). 24x24 convs use
// overlapping 16x8 tiles + split-K4. mfgemm pad 36->40.
// ---------------------------------------------------------------------------

static constexpr int THW  = 1728;
static constexpr int HW16 = 576;

typedef __attribute__((ext_vector_type(8))) short bf16x8;
typedef __attribute__((ext_vector_type(4))) float f32x4;
typedef unsigned int uint;

__device__ __forceinline__ float sigmf(float x) { return 1.f / (1.f + expf(-x)); }

__device__ __forceinline__ float bf2f(unsigned short u) {
  union { float f; uint i; } x; x.i = ((uint)u) << 16; return x.f;
}
__device__ __forceinline__ unsigned short f2bf(float f) {
  union { float f; uint i; } x; x.f = f;
  uint r = x.i + 0x7fffu + ((x.i >> 16) & 1u);
  return (unsigned short)(r >> 16);
}
__device__ __forceinline__ uint relu2(uint x) {
  uint lo = (x & 0x8000u) ? 0u : (x & 0xFFFFu);
  uint hi = (x & 0x80000000u) ? 0u : (x & 0xFFFF0000u);
  return lo | hi;
}
__device__ __forceinline__ bf16x8 lds_ld8(const unsigned short* p) {
  union { uint4 u4; bf16x8 v; } x;
  x.u4 = *(const uint4*)(p);       // 16B-aligned (pad-40 rows)
  return x.v;
}

// ---------------- NCHW fp32 -> NHWC bf16 transpose -------------------------
__global__ __launch_bounds__(256) void tr_k(const float* __restrict__ in,
                                            unsigned short* __restrict__ out,
                                            int C, int HW) {
  __shared__ float t[32][33];
  int p0 = blockIdx.x << 5, c0 = blockIdx.y << 5, b = blockIdx.z;
  int tx = threadIdx.x & 31, ty = threadIdx.x >> 5;
  const float* ib = in + (size_t)b * C * HW;
  #pragma unroll
  for (int e = 0; e < 4; ++e)
    t[ty + e * 8][tx] = ib[(size_t)(c0 + ty + e * 8) * HW + p0 + tx];
  __syncthreads();
  unsigned short* ob = out + (size_t)b * C * HW;
  #pragma unroll
  for (int e = 0; e < 4; ++e)
    ob[(size_t)(p0 + ty + e * 8) * C + c0 + tx] = f2bf(t[tx][ty + e * 8]);
}

// ---------------- elementwise fp32 -> bf16 ---------------------------------
__global__ __launch_bounds__(256) void cvt_k(const float* __restrict__ in,
                                             unsigned short* __restrict__ o, int n) {
  int i = blockIdx.x * 256 + threadIdx.x;
  if (i < n) o[i] = f2bf(in[i]);
}

// ---------------- asq[b][t] = sum_c mkT[b][t][c]^2  (bf16 rows) ------------
__global__ __launch_bounds__(256) void asq2_k(const unsigned short* __restrict__ mkT,
                                              float* __restrict__ asq) {
  int row = blockIdx.x * 4 + (threadIdx.x >> 6);
  int lane = threadIdx.x & 63;
  const unsigned short* p = mkT + (size_t)row * 512;
  float s = 0.f;
  #pragma unroll
  for (int i = 0; i < 8; ++i) { float v = bf2f(p[lane + (i << 6)]); s += v * v; }
  #pragma unroll
  for (int m = 32; m > 0; m >>= 1) s += __shfl_xor(s, m);
  if (lane == 0) asq[row] = s;
}

// ---------------- bf16 MFMA GEMM: A[M][K], B[N][K], both k-major -----------
template<int EPI, int SPLIT>
__global__ __launch_bounds__(256) void mfgemm_k(
    const unsigned short* __restrict__ A, const unsigned short* __restrict__ Bm,
    float* __restrict__ C, const float* __restrict__ asq,
    int K, int ldc, int Nt, size_t aBS, size_t bBS, size_t cBS, float scale)
{
  const int by = blockIdx.y;
  const int b = by & 3, split = by >> 2;
  const int mt = blockIdx.x / Nt, nt = blockIdx.x - mt * Nt;
  const int m0 = mt << 6, n0 = nt << 6;
  const unsigned short* Ab = A + (size_t)b * aBS + (size_t)m0 * K;
  const unsigned short* Bb = Bm + (size_t)b * bBS + (size_t)n0 * K;
  __shared__ unsigned short sA[64][40];
  __shared__ unsigned short sB[64][40];
  const int tid = threadIdx.x;
  const int lane = tid & 63, wv = tid >> 6;
  const int mS = (wv >> 1) << 5, nS = (wv & 1) << 5;
  const int l15 = lane & 15, lq = lane >> 4;
  const int srow = tid >> 2, scol = (tid & 3) << 3;
  f32x4 acc[2][2];
  #pragma unroll
  for (int i = 0; i < 2; ++i)
    #pragma unroll
    for (int j = 0; j < 2; ++j) acc[i][j] = (f32x4){0.f, 0.f, 0.f, 0.f};
  const int Kper = K / SPLIT;
  const int kLo = split * Kper, kHi = kLo + Kper;
  for (int k0 = kLo; k0 < kHi; k0 += 32) {
    uint4 va = *(const uint4*)(Ab + (size_t)srow * K + k0 + scol);
    uint4 vb = *(const uint4*)(Bb + (size_t)srow * K + k0 + scol);
    *(uint4*)&sA[srow][scol] = va;
    *(uint4*)&sB[srow][scol] = vb;
    __syncthreads();
    bf16x8 a0 = lds_ld8(&sA[mS + l15][lq << 3]);
    bf16x8 a1 = lds_ld8(&sA[mS + 16 + l15][lq << 3]);
    bf16x8 b0 = lds_ld8(&sB[nS + l15][lq << 3]);
    bf16x8 b1 = lds_ld8(&sB[nS + 16 + l15][lq << 3]);
    acc[0][0] = __builtin_amdgcn_mfma_f32_16x16x32_bf16(a0, b0, acc[0][0], 0, 0, 0);
    acc[0][1] = __builtin_amdgcn_mfma_f32_16x16x32_bf16(a0, b1, acc[0][1], 0, 0, 0);
    acc[1][0] = __builtin_amdgcn_mfma_f32_16x16x32_bf16(a1, b0, acc[1][0], 0, 0, 0);
    acc[1][1] = __builtin_amdgcn_mfma_f32_16x16x32_bf16(a1, b1, acc[1][1], 0, 0, 0);
    __syncthreads();
  }
  float* Cb = C + (size_t)(EPI == 2 ? (split * 4 + b) : b) * cBS;
  #pragma unroll
  for (int i = 0; i < 2; ++i) {
    const int mrow = m0 + mS + i * 16 + (lq << 2);
    #pragma unroll
    for (int j = 0; j < 2; ++j) {
      const int n = n0 + nS + j * 16 + l15;
      float4 v;
      if constexpr (EPI == 1) {
        float4 aq = *(const float4*)(asq + b * THW + mrow);
        v.x = (2.f * acc[i][j][0] - aq.x) * scale;
        v.y = (2.f * acc[i][j][1] - aq.y) * scale;
        v.z = (2.f * acc[i][j][2] - aq.z) * scale;
        v.w = (2.f * acc[i][j][3] - aq.w) * scale;
      } else {
        v.x = acc[i][j][0]; v.y = acc[i][j][1];
        v.z = acc[i][j][2]; v.w = acc[i][j][3];
      }
      *(float4*)(Cb + (size_t)n * ldc + mrow) = v;
    }
  }
}

// ---------------- row softmax: S^T[row][1728] fp32 -> P bf16 normalized ----
__global__ __launch_bounds__(256) void softmaxT_k(const float* __restrict__ S,
                                                  unsigned short* __restrict__ P) {
  int row = blockIdx.x * 4 + (threadIdx.x >> 6);
  int lane = threadIdx.x & 63;
  const float* sp = S + (size_t)row * THW;
  float v[27];
  float mx = -3.0e38f;
  #pragma unroll
  for (int i = 0; i < 27; ++i) { v[i] = sp[lane + (i << 6)]; mx = fmaxf(mx, v[i]); }
  #pragma unroll
  for (int m = 32; m > 0; m >>= 1) mx = fmaxf(mx, __shfl_xor(mx, m));
  float sum = 0.f;
  #pragma unroll
  for (int i = 0; i < 27; ++i) { v[i] = expf(v[i] - mx); sum += v[i]; }
  #pragma unroll
  for (int m = 32; m > 0; m >>= 1) sum += __shfl_xor(sum, m);
  float inv = 1.f / sum;
  unsigned short* pp = P + (size_t)row * THW;
  #pragma unroll
  for (int i = 0; i < 27; ++i) pp[lane + (i << 6)] = f2bf(v[i] * inv);
}

// ---------------- readout split-K=3 reduce -> fusion NHWC ------------------
__global__ __launch_bounds__(256) void skred3_k(const float* __restrict__ part,
                                                float* __restrict__ fusion, int cOff) {
  int i = blockIdx.x * 256 + threadIdx.x;
  if (i >= 4 * HW16 * 512) return;
  const int N = 4 * HW16 * 512;
  float v = part[i] + part[i + N] + part[i + 2 * N];
  int c = i & 511; int t = i >> 9; int n = t % HW16; int b = t / HW16;
  fusion[((size_t)b * HW16 + n) * 1536 + cOff + c] = v;
}

// ---------------- pool over pixels of NHWC fusion --------------------------
__global__ __launch_bounds__(128) void pool_k(const float* __restrict__ f,
                                              float* __restrict__ pool) {
  int b = blockIdx.y, c = blockIdx.x * 128 + threadIdx.x;
  const float* p = f + (size_t)b * HW16 * 1536 + c;
  float s = 0.f;
  for (int n = 0; n < HW16; ++n) s += p[(size_t)n * 1536];
  pool[b * 1536 + c] = s * (1.f / 576.f);
}

__global__ __launch_bounds__(256) void fusionp_k(const float* __restrict__ f,
                                                 const float* __restrict__ pool,
                                                 unsigned short* __restrict__ o, int total) {
  int i = blockIdx.x * 256 + threadIdx.x;
  if (i >= total) return;
  int c = i % 1536; int b = i / (HW16 * 1536);
  o[i] = f2bf(f[i] + pool[b * 1536 + c]);
}

// dec NHWC bf16 [b][n][1024]
__global__ __launch_bounds__(256) void decodes_k(const float* __restrict__ fusion,
                                                 const unsigned short* __restrict__ m,
                                                 const float* __restrict__ qv,
                                                 unsigned short* __restrict__ o) {
  int i = blockIdx.x * 256 + threadIdx.x;
  if (i >= 4 * HW16 * 1024) return;
  int c = i & 1023; int t = i >> 10; int n = t % HW16; int b = t / HW16;
  float v;
  if (c < 512) {
    const float* f = fusion + ((size_t)b * HW16 + n) * 1536;
    float s3 = f[c] + f[c + 512] + f[c + 1024];
    float mf = bf2f(m[((size_t)b * HW16 + n) * 512 + c]);
    v = s3 * (mf + 1.f);
  } else {
    v = qv[((size_t)b * 512 + (c - 512)) * HW16 + n];
  }
  o[i] = f2bf(v);
}

// ---------------- weight repack OIHW fp32 -> [tap][co][ci] bf16 ------------
__global__ __launch_bounds__(256) void wrep_k(const float* __restrict__ w,
                                              unsigned short* __restrict__ o,
                                              int Cout, int Cin, int total) {
  int i = blockIdx.x * 256 + threadIdx.x;
  if (i >= total) return;
  int ci = i % Cin; int t = i / Cin; int co = t % Cout; int tap = t / Cout;
  o[i] = f2bf(w[((size_t)co * Cin + ci) * 9 + tap]);
}

// ---------------- MFMA conv3x3 v2: 128co x 128pix, 64x64 per wave ----------
// Pixel tile 16w x 8h (overlapping tiles when W%16 != 0; duplicate outputs are
// bit-identical -> only used with SPLITK at W=24). ky-row weight staging.
template<bool RELU_IN, int ACT, bool SPLITK, bool HAS_ADD>
__global__ __launch_bounds__(256) void convmf2_k(
    const unsigned short* __restrict__ in, const unsigned short* __restrict__ W2,
    const float* __restrict__ bias, const unsigned short* __restrict__ add,
    unsigned short* __restrict__ outb, float* __restrict__ outp,
    int Cin, int Cout, int H, int W, int ciPer)
{
  const int xT = (W + 15) >> 4;
  const int xt = blockIdx.x % xT, yt = blockIdx.x / xT;
  int tx0 = xt << 4; if (tx0 > W - 16) tx0 = W - 16;
  const int ty0 = yt << 3;
  const int co0 = blockIdx.y << 7;
  const int b = blockIdx.z & 3;
  const int split = blockIdx.z >> 2;
  const int HWp = H * W;
  __shared__ unsigned short sA[3][128][40];   // [kx][co][ci32] one ky row
  __shared__ unsigned short sB[180][40];      // 18x10 halo x 32 ci
  const int tid = threadIdx.x;
  const int lane = tid & 63, wv = tid >> 6;
  const int coQ = (wv >> 1) << 6;   // 0/64
  const int nQ  = (wv & 1) << 6;    // 0/64
  const int l15 = lane & 15, lq = lane >> 4;
  int rowb[4], gp[4];
  #pragma unroll
  for (int j = 0; j < 4; ++j) {
    int n = nQ + 16 * j + l15;
    int py = n >> 4, px = n & 15;
    rowb[j] = py * 18 + px;
    gp[j] = (ty0 + py) * W + tx0 + px;
  }
  f32x4 acc[4][4];
  #pragma unroll
  for (int i = 0; i < 4; ++i)
    #pragma unroll
    for (int j = 0; j < 4; ++j) acc[i][j] = (f32x4){0.f, 0.f, 0.f, 0.f};
  const size_t inBase = (size_t)b * HWp * Cin;
  const int kLo = split * ciPer, kHi = kLo + ciPer;
  for (int k0 = kLo; k0 < kHi; k0 += 32) {
    #pragma unroll
    for (int ky = 0; ky < 3; ++ky) {
      __syncthreads();                       // prior window reads done
      if (ky == 0) {                         // stage halo (once per ci-chunk)
        #pragma unroll
        for (int e = 0; e < 3; ++e) {
          int idx = tid + (e << 8);
          if (idx < 720) {
            int hp = idx >> 2, c8 = (idx & 3) << 3;
            int hy = ty0 + hp / 18 - 1;
            int hx = tx0 + hp % 18 - 1;
            uint4 v = make_uint4(0u, 0u, 0u, 0u);
            if (hy >= 0 && hy < H && hx >= 0 && hx < W)
              v = *(const uint4*)(in + inBase + (size_t)(hy * W + hx) * Cin + k0 + c8);
            if (RELU_IN) { v.x = relu2(v.x); v.y = relu2(v.y); v.z = relu2(v.z); v.w = relu2(v.w); }
            *(uint4*)&sB[hp][c8] = v;
          }
        }
      }
      // stage one ky row of weights: 3 taps x 128 co x 32 ci
      #pragma unroll
      for (int e = 0; e < 6; ++e) {
        int idx = tid + (e << 8);
        int kx = idx >> 9;
        int rem = idx & 511;
        int co = rem >> 2, c8 = (rem & 3) << 3;
        uint4 v = *(const uint4*)(W2 + ((size_t)((ky * 3 + kx) * Cout + co0 + co) * Cin + k0 + c8));
        *(uint4*)&sA[kx][co][c8] = v;
      }
      __syncthreads();
      #pragma unroll
      for (int kx = 0; kx < 3; ++kx) {
        bf16x8 a[4], bb[4];
        #pragma unroll
        for (int i = 0; i < 4; ++i)
          a[i] = lds_ld8(&sA[kx][coQ + 16 * i + l15][lq << 3]);
        #pragma unroll
        for (int j = 0; j < 4; ++j)
          bb[j] = lds_ld8(&sB[rowb[j] + ky * 18 + kx][lq << 3]);
        #pragma unroll
        for (int i = 0; i < 4; ++i)
          #pragma unroll
          for (int j = 0; j < 4; ++j)
            acc[i][j] = __builtin_amdgcn_mfma_f32_16x16x32_bf16(a[i], bb[j], acc[i][j], 0, 0, 0);
      }
    }
  }
  #pragma unroll
  for (int i = 0; i < 4; ++i) {
    const int coB = co0 + coQ + 16 * i + (lq << 2);
    #pragma unroll
    for (int j = 0; j < 4; ++j) {
      if constexpr (SPLITK) {
        float* dst = outp + ((size_t)(split * 4 + b) * HWp + gp[j]) * Cout + coB;
        float4 v; v.x = acc[i][j][0]; v.y = acc[i][j][1]; v.z = acc[i][j][2]; v.w = acc[i][j][3];
        *(float4*)dst = v;
      } else {
        float4 bv = *(const float4*)(bias + coB);
        float v0 = acc[i][j][0] + bv.x, v1 = acc[i][j][1] + bv.y;
        float v2 = acc[i][j][2] + bv.z, v3 = acc[i][j][3] + bv.w;
        const size_t base = ((size_t)b * HWp + gp[j]) * Cout + coB;
        if constexpr (HAS_ADD) {
          ushort4 a4 = *(const ushort4*)(add + base);
          v0 += bf2f(a4.x); v1 += bf2f(a4.y); v2 += bf2f(a4.z); v3 += bf2f(a4.w);
        }
        if constexpr (ACT == 1) { v0 = sigmf(v0); v1 = sigmf(v1); v2 = sigmf(v2); v3 = sigmf(v3); }
        ushort4 o; o.x = f2bf(v0); o.y = f2bf(v1); o.z = f2bf(v2); o.w = f2bf(v3);
        *(ushort4*)(outb + base) = o;
      }
    }
  }
}

// ---------------- split-K reduce + epilogue --------------------------------
template<int NS, int ACT, bool HAS_ADD>
__global__ __launch_bounds__(256) void skred_k(
    const float* __restrict__ part, const float* __restrict__ bias,
    const unsigned short* __restrict__ add, unsigned short* __restrict__ out,
    int Cout, int n)
{
  int i = blockIdx.x * 256 + threadIdx.x;
  if (i >= n) return;
  float v = bias[i % Cout];
  #pragma unroll
  for (int s = 0; s < NS; ++s) v += part[i + (size_t)s * n];
  if (HAS_ADD) v += bf2f(add[i]);
  if (ACT == 1) v = sigmf(v);
  out[i] = f2bf(v);
}

// ---------------- s += bilinear 2x upsample (NHWC bf16) --------------------
__global__ __launch_bounds__(256) void up2add_k(unsigned short* __restrict__ s,
                                                const unsigned short* __restrict__ x,
                                                int OH, int OW, int C, int total) {
  int i = blockIdx.x * 256 + threadIdx.x;
  if (i >= total) return;
  int c = i % C; int op = i / C;
  int ox = op % OW; int t = op / OW; int oy = t % OH; int b = t / OH;
  int IH = OH >> 1, IW = OW >> 1;
  const unsigned short* xp = x + ((size_t)b * IH * IW) * C + c;
  float uy = 0.5f * oy - 0.25f;
  float ux = 0.5f * ox - 0.25f;
  int y0 = (int)floorf(uy); float fy = uy - (float)y0;
  int x0 = (int)floorf(ux); float fx = ux - (float)x0;
  int y0c = y0 < 0 ? 0 : y0; int y1c = (y0 + 1 >= IH) ? IH - 1 : y0 + 1;
  int x0c = x0 < 0 ? 0 : x0; int x1c = (x0 + 1 >= IW) ? IW - 1 : x0 + 1;
  float v00 = bf2f(xp[(size_t)(y0c * IW + x0c) * C]);
  float v01 = bf2f(xp[(size_t)(y0c * IW + x1c) * C]);
  float v10 = bf2f(xp[(size_t)(y1c * IW + x0c) * C]);
  float v11 = bf2f(xp[(size_t)(y1c * IW + x1c) * C]);
  float r = (1.f - fy) * ((1.f - fx) * v00 + fx * v01)
          + fy * ((1.f - fx) * v10 + fx * v11);
  s[i] = f2bf(bf2f(s[i]) + r);
}

// ---------------- pred head: 256->1 conv, relu-in, NHWC bf16 ---------------
__global__ __launch_bounds__(256) void pred_k(const unsigned short* __restrict__ in,
                                              const float* __restrict__ w,
                                              const float* __restrict__ bias,
                                              float* __restrict__ l4) {
  __shared__ float sw[9][256];
  for (int idx = threadIdx.x; idx < 2304; idx += 256)
    sw[idx % 9][idx / 9] = w[idx];
  __syncthreads();
  int gpix = blockIdx.x * 4 + (threadIdx.x >> 6);
  int b = gpix / 9216, pix = gpix % 9216;
  int py = pix / 96, px = pix % 96;
  int lane = threadIdx.x & 63;
  float acc = 0.f;
  #pragma unroll
  for (int ky = 0; ky < 3; ++ky) {
    int gy = py + ky - 1; if (gy < 0 || gy > 95) continue;
    #pragma unroll
    for (int kx = 0; kx < 3; ++kx) {
      int gx = px + kx - 1; if (gx < 0 || gx > 95) continue;
      const unsigned short* ip = in + ((size_t)b * 9216 + gy * 96 + gx) * 256;
      const float* wp = sw[ky * 3 + kx];
      #pragma unroll
      for (int cq = 0; cq < 4; ++cq) {
        int c = lane + (cq << 6);
        acc += fmaxf(bf2f(ip[c]), 0.f) * wp[c];
      }
    }
  }
  #pragma unroll
  for (int off = 32; off > 0; off >>= 1) acc += __shfl_down(acc, off);
  if (lane == 0) l4[gpix] = acc + bias[0];
}

// ---------------- bilinear 4x + sigmoid/aggregate/output -------------------
__global__ __launch_bounds__(256) void final_k(const float* __restrict__ l4,
                                               float* __restrict__ out) {
  int i = blockIdx.x * 256 + threadIdx.x;
  if (i >= 4 * 384 * 384) return;
  int ox = i % 384; int t = i / 384; int oy = t % 384; int b = t / 384;
  const float* lp = l4 + (size_t)b * 96 * 96;
  float uy = 0.25f * oy - 0.375f;
  float ux = 0.25f * ox - 0.375f;
  int y0 = (int)floorf(uy); float fy = uy - (float)y0;
  int x0 = (int)floorf(ux); float fx = ux - (float)x0;
  int y0c = y0 < 0 ? 0 : y0; int y1c = (y0 + 1 > 95) ? 95 : y0 + 1;
  int x0c = x0 < 0 ? 0 : x0; int x1c = (x0 + 1 > 95) ? 95 : x0 + 1;
  float l = (1.f - fy) * ((1.f - fx) * lp[y0c * 96 + x0c] + fx * lp[y0c * 96 + x1c])
          + fy * ((1.f - fx) * lp[y1c * 96 + x0c] + fx * lp[y1c * 96 + x1c]);
  float p  = 1.f / (1.f + expf(-l));
  float p1 = fminf(fmaxf(p, 1e-7f), 1.f - 1e-7f);
  float p0 = fminf(fmaxf(1.f - p, 1e-7f), 1.f - 1e-7f);
  float L0 = logf(p0 / (1.f - p0));
  float L1 = logf(p1 / (1.f - p1));
  int sp = oy * 384 + ox;
  out[(size_t)(b * 2) * 147456 + sp] = L0;
  out[(size_t)(b * 2 + 1) * 147456 + sp] = L1;
  out[(size_t)1179648 + (size_t)b * 147456 + sp] = 1.f / (1.f + expf(L0 - L1));
}

// ---------------------------------------------------------------------------
extern "C" void kernel_launch(void* const* d_in, const int* in_sizes, int n_in,
                              void* d_out, int out_size, void* d_ws, size_t ws_size,
                              hipStream_t stream)
{
  (void)in_sizes; (void)n_in; (void)out_size; (void)ws_size;
  const float* qk16   = (const float*)d_in[0];
  const float* qv16   = (const float*)d_in[1];
  const float* qf8    = (const float*)d_in[2];
  const float* qf4    = (const float*)d_in[3];
  const float* mk16   = (const float*)d_in[4];
  const float* mv16   = (const float*)d_in[5];
  const float* firstk = (const float*)d_in[6];
  const float* firstv = (const float*)d_in[7];
  const float* adjk   = (const float*)d_in[8];
  const float* adfv   = (const float*)d_in[9];
  const float* mask_w   = (const float*)d_in[10];
  const float* mask_b   = (const float*)d_in[11];
  const float* cmp_ds_w = (const float*)d_in[12];
  const float* cmp_ds_b = (const float*)d_in[13];
  const float* cmp_c1_w = (const float*)d_in[14];
  const float* cmp_c1_b = (const float*)d_in[15];
  const float* cmp_c2_w = (const float*)d_in[16];
  const float* cmp_c2_b = (const float*)d_in[17];
  const float* u1_skip_w = (const float*)d_in[18];
  const float* u1_skip_b = (const float*)d_in[19];
  const float* u1_ds_w   = (const float*)d_in[20];
  const float* u1_ds_b   = (const float*)d_in[21];
  const float* u1_c1_w   = (const float*)d_in[22];
  const float* u1_c1_b   = (const float*)d_in[23];
  const float* u1_c2_w   = (const float*)d_in[24];
  const float* u1_c2_b   = (const float*)d_in[25];
  const float* u2_skip_w = (const float*)d_in[26];
  const float* u2_skip_b = (const float*)d_in[27];
  const float* u2_c1_w   = (const float*)d_in[28];
  const float* u2_c1_b   = (const float*)d_in[29];
  const float* u2_c2_w   = (const float*)d_in[30];
  const float* u2_c2_b   = (const float*)d_in[31];
  const float* pred_w    = (const float*)d_in[32];
  const float* pred_b    = (const float*)d_in[33];
  float* out = (float*)d_out;

  // ---- workspace layout (byte offsets), ~92.2 MB ----
  char* wsb = (char*)d_ws;
  unsigned short* Wsl = (unsigned short*)(wsb);            // 23,592,960 B
  char* slA = wsb + 23592960;                              // 18,874,368
  char* slB = wsb + 42467328;                              // 18,874,368
  char* slC = wsb + 61341696;                              //  9,437,184
  char* slD = wsb + 70778880;                              //  9,437,184
  char* slE = wsb + 80216064;                              //  4,718,592
  char* slF = wsb + 84934656;                              //  4,718,592
  char* slG = wsb + 89653248;                              //  2,359,296
  char* slS = wsb + 92012544;                              //  ~208,896

  // affinity-phase aliases
  unsigned short* mkT = Wsl;
  unsigned short* mvb = Wsl + 3538944;
  unsigned short* qkT = Wsl + 7077888;
  float* aff      = (float*)slA;
  float* rpart    = (float*)slA;
  unsigned short* Pmat = (unsigned short*)slC;
  float* fusion   = (float*)slB;
  // conv-phase aliases
  float* partial  = (float*)slA;       // split-K partials (<= 18.87 MB)
  unsigned short* qf8t    = (unsigned short*)slC;
  unsigned short* x8      = (unsigned short*)slC;
  unsigned short* fusionp = (unsigned short*)slD;
  unsigned short* s8      = (unsigned short*)slD;
  unsigned short* dec     = (unsigned short*)slE;
  unsigned short* t1_8    = (unsigned short*)slE;
  unsigned short* t1      = (unsigned short*)slF;
  unsigned short* t2      = (unsigned short*)(slF + 2359296);
  unsigned short* t2_8    = (unsigned short*)slF;
  unsigned short* mbuf    = (unsigned short*)slG;
  unsigned short* x16     = (unsigned short*)slG;
  unsigned short* qf4t    = (unsigned short*)slA;   // after u1 partials dead
  unsigned short* t1_4    = (unsigned short*)slA;
  unsigned short* s4      = (unsigned short*)slB;
  float* asqb   = (float*)slS;
  float* poolb  = (float*)(slS + 36864);
  float* l4     = (float*)(slS + 61440);

  const float scale = 0.04419417382415922f;   // 1/sqrt(512)

  // ---- affinity pipeline (bf16 MFMA), fusion NHWC [b][n][1536] fp32 ----
  tr_k<<<dim3(18, 16, 4), 256, 0, stream>>>(qk16, qkT, 512, 576);
  const float* banksK[3] = {mk16, firstk, adjk};
  const float* banksV[3] = {mv16, firstv, adfv};
  for (int bank = 0; bank < 3; ++bank) {
    tr_k<<<dim3(54, 16, 4), 256, 0, stream>>>(banksK[bank], mkT, 512, 1728);
    asq2_k<<<1728, 256, 0, stream>>>(mkT, asqb);
    mfgemm_k<1, 1><<<dim3(243, 4), 256, 0, stream>>>(
        mkT, qkT, aff, asqb, 512, THW, 9,
        (size_t)THW * 512, (size_t)HW16 * 512, (size_t)HW16 * THW, scale);
    softmaxT_k<<<576, 256, 0, stream>>>(aff, Pmat);
    cvt_k<<<(3538944 + 255) / 256, 256, 0, stream>>>(banksV[bank], mvb, 3538944);
    mfgemm_k<2, 3><<<dim3(72, 12), 256, 0, stream>>>(
        mvb, Pmat, rpart, nullptr, 1728, 512, 9,
        (size_t)512 * THW, (size_t)HW16 * THW, (size_t)HW16 * 512, 0.f);
    skred3_k<<<(1179648 + 255) / 256, 256, 0, stream>>>(rpart, fusion, bank * 512);
  }

  pool_k<<<dim3(12, 4), 128, 0, stream>>>(fusion, poolb);
  fusionp_k<<<(3538944 + 255) / 256, 256, 0, stream>>>(fusion, poolb, fusionp, 3538944);

  // ---- mask conv (1536->512 @24x24, sigmoid), split-K=4 ----
  wrep_k<<<(7077888 + 255) / 256, 256, 0, stream>>>(mask_w, Wsl, 512, 1536, 7077888);
  convmf2_k<false, 0, true, false><<<dim3(6, 4, 16), 256, 0, stream>>>(
      fusionp, Wsl, nullptr, nullptr, nullptr, partial, 1536, 512, 24, 24, 384);
  skred_k<4, 1, false><<<(1179648 + 255) / 256, 256, 0, stream>>>(
      partial, mask_b, nullptr, mbuf, 512, 1179648);

  decodes_k<<<(2359296 + 255) / 256, 256, 0, stream>>>(fusion, mbuf, qv16, dec);

  // ---- cmp resblock (24x24), split-K=4 ----
  wrep_k<<<(4718592 + 255) / 256, 256, 0, stream>>>(cmp_c1_w, Wsl, 512, 1024, 4718592);
  wrep_k<<<(2359296 + 255) / 256, 256, 0, stream>>>(cmp_c2_w, Wsl + 4718592, 512, 512, 2359296);
  wrep_k<<<(4718592 + 255) / 256, 256, 0, stream>>>(cmp_ds_w, Wsl + 7077888, 512, 1024, 4718592);
  convmf2_k<true, 0, true, false><<<dim3(6, 4, 16), 256, 0, stream>>>(
      dec, Wsl, nullptr, nullptr, nullptr, partial, 1024, 512, 24, 24, 256);
  skred_k<4, 0, false><<<(1179648 + 255) / 256, 256, 0, stream>>>(
      partial, cmp_c1_b, nullptr, t1, 512, 1179648);
  convmf2_k<true, 0, true, false><<<dim3(6, 4, 16), 256, 0, stream>>>(
      t1, Wsl + 4718592, nullptr, nullptr, nullptr, partial, 512, 512, 24, 24, 128);
  skred_k<4, 0, false><<<(1179648 + 255) / 256, 256, 0, stream>>>(
      partial, cmp_c2_b, nullptr, t2, 512, 1179648);
  convmf2_k<false, 0, true, false><<<dim3(6, 4, 16), 256, 0, stream>>>(
      dec, Wsl + 7077888, nullptr, nullptr, nullptr, partial, 1024, 512, 24, 24, 256);
  skred_k<4, 0, true><<<(1179648 + 255) / 256, 256, 0, stream>>>(
      partial, cmp_ds_b, t2, x16, 512, 1179648);

  // ---- u1 stage (48x48) ----
  tr_k<<<dim3(72, 16, 4), 256, 0, stream>>>(qf8, qf8t, 512, 2304);
  wrep_k<<<(2359296 + 255) / 256, 256, 0, stream>>>(u1_skip_w, Wsl, 512, 512, 2359296);
  wrep_k<<<(1179648 + 255) / 256, 256, 0, stream>>>(u1_c1_w, Wsl + 2359296, 256, 512, 1179648);
  wrep_k<<<(589824 + 255) / 256, 256, 0, stream>>>(u1_c2_w, Wsl + 3538944, 256, 256, 589824);
  wrep_k<<<(1179648 + 255) / 256, 256, 0, stream>>>(u1_ds_w, Wsl + 4128768, 256, 512, 1179648);
  convmf2_k<false, 0, false, false><<<dim3(18, 4, 4), 256, 0, stream>>>(
      qf8t, Wsl, u1_skip_b, nullptr, s8, nullptr, 512, 512, 48, 48, 512);
  up2add_k<<<(4718592 + 255) / 256, 256, 0, stream>>>(s8, x16, 48, 48, 512, 4718592);
  convmf2_k<true, 0, true, false><<<dim3(18, 2, 8), 256, 0, stream>>>(
      s8, Wsl + 2359296, nullptr, nullptr, nullptr, partial, 512, 256, 48, 48, 256);
  skred_k<2, 0, false><<<(2359296 + 255) / 256, 256, 0, stream>>>(
      partial, u1_c1_b, nullptr, t1_8, 256, 2359296);
  convmf2_k<true, 0, true, false><<<dim3(18, 2, 8), 256, 0, stream>>>(
      t1_8, Wsl + 3538944, nullptr, nullptr, nullptr, partial, 256, 256, 48, 48, 128);
  skred_k<2, 0, false><<<(2359296 + 255) / 256, 256, 0, stream>>>(
      partial, u1_c2_b, nullptr, t2_8, 256, 2359296);
  convmf2_k<false, 0, true, false><<<dim3(18, 2, 8), 256, 0, stream>>>(
      s8, Wsl + 4128768, nullptr, nullptr, nullptr, partial, 512, 256, 48, 48, 256);
  skred_k<2, 0, true><<<(2359296 + 255) / 256, 256, 0, stream>>>(
      partial, u1_ds_b, t2_8, x8, 256, 2359296);

  // ---- u2 stage (96x96) ----
  tr_k<<<dim3(288, 8, 4), 256, 0, stream>>>(qf4, qf4t, 256, 9216);
  wrep_k<<<(589824 + 255) / 256, 256, 0, stream>>>(u2_skip_w, Wsl, 256, 256, 589824);
  wrep_k<<<(589824 + 255) / 256, 256, 0, stream>>>(u2_c1_w, Wsl + 589824, 256, 256, 589824);
  wrep_k<<<(589824 + 255) / 256, 256, 0, stream>>>(u2_c2_w, Wsl + 1179648, 256, 256, 589824);
  convmf2_k<false, 0, false, false><<<dim3(72, 2, 4), 256, 0, stream>>>(
      qf4t, Wsl, u2_skip_b, nullptr, s4, nullptr, 256, 256, 96, 96, 256);
  up2add_k<<<(9437184 + 255) / 256, 256, 0, stream>>>(s4, x8, 96, 96, 256, 9437184);
  convmf2_k<true, 0, false, false><<<dim3(72, 2, 4), 256, 0, stream>>>(
      s4, Wsl + 589824, u2_c1_b, nullptr, t1_4, nullptr, 256, 256, 96, 96, 256);
  convmf2_k<true, 0, false, true><<<dim3(72, 2, 4), 256, 0, stream>>>(
      t1_4, Wsl + 1179648, u2_c2_b, s4, s4, nullptr, 256, 256, 96, 96, 256);

  pred_k<<<9216, 256, 0, stream>>>(s4, pred_w, pred_b, l4);
  final_k<<<(589824 + 255) / 256, 256, 0, stream>>>(l4, out);
}